// Round 6
// baseline (584.004 us; speedup 1.0000x reference)
//
#include <hip/hip_runtime.h>

typedef _Float16 f16;
typedef _Float16 f16x2 __attribute__((ext_vector_type(2)));
typedef _Float16 f16x4 __attribute__((ext_vector_type(4)));
typedef _Float16 f16x8 __attribute__((ext_vector_type(8)));
typedef float floatx4 __attribute__((ext_vector_type(4)));

#define MFMA(a, b, c) __builtin_amdgcn_mfma_f32_16x16x32_f16((a), (b), (c), 0, 0, 0)
#define MFMA16(a, b, c) __builtin_amdgcn_mfma_f32_16x16x16f16((a), (b), (c), 0, 0, 0)
#define PRIO1() __builtin_amdgcn_s_setprio(1)
#define PRIO0() __builtin_amdgcn_s_setprio(0)

// Problem constants
constexpr int S = 35;        // 1 cls + 24 dims + 10 mem  (ONE batch item per block now)
constexpr int NH = 8;
constexpr int NL = 3;
constexpr int RP = 48;       // padded rows (35 -> 3 row-tiles)
constexpr int MT = 3;        // MFMA row-tiles
constexpr int BUF = RP * 64; // 3072 elems per swizzled 48x64 buffer
constexpr int SEQOFF = 4096 * 128;                 // 524288
constexpr int MEMOFF = SEQOFF + 4096 * 24 * 64;    // 6815744
constexpr int TOKPOS_OFF = 245760;                 // f16 elems into ws; tokpos floats live there
constexpr float QSCL = 0.51006982f;                // 1/sqrt(8) * log2(e), folded into Wq at cvt

// XOR swizzle: 8-col groups rotated by row&7 -> stride-64 rows, conflict-free patterns
__device__ __forceinline__ int sw64(int r, int c) {
    return (r << 6) + ((((c >> 3) ^ r) & 7) << 3) + (c & 7);
}
__device__ __forceinline__ int sw128(int r, int c) {
    return (r << 7) + ((((c >> 3) ^ (r & 7))) << 3) + (c & 7);
}

struct Params {
    const int* tok;
    const float *traits, *relg, *mem, *temb, *demb, *traitW, *traitb, *intentW, *intentb, *cls;
    const float *bqkv, *bo, *ln1g, *ln1b, *b1, *b2, *ln2g, *ln2b;
    const float *outW, *outb, *olng, *olnb;
    const f16 *Wqkv, *Wo, *W1, *W2;   // converted into d_ws
    const float* tokpos;              // precomputed in d_ws
    float* out;
};

// fp32->f16 weight conversion (Wq rows prescaled by QSCL) + tokpos precompute (block 240)
__global__ void cvt_all(const float* __restrict__ wqkv, const float* __restrict__ wo,
                        const float* __restrict__ w1, const float* __restrict__ w2,
                        const int* __restrict__ tok, const float* __restrict__ temb,
                        const float* __restrict__ demb, const float* __restrict__ traitb,
                        const float* __restrict__ intentb, f16* __restrict__ dst) {
    if (blockIdx.x == 240) {
        // tokpos[s][d] = mean_t temb[tok[s,t]][d] + demb[s][d] + traitb[d] + intentb[d]
        float* tp = (float*)(dst + TOKPOS_OFF);
        for (int idx = threadIdx.x; idx < 24 * 64; idx += 256) {
            int s = idx >> 6, d = idx & 63;
            float a = 0.f;
#pragma unroll
            for (int t = 0; t < 8; ++t) a += temb[tok[s * 8 + t] * 64 + d];
            tp[idx] = a * 0.125f + demb[idx] + traitb[d] + intentb[d];
        }
        return;
    }
    int i = (blockIdx.x * 256 + threadIdx.x) * 4;
    const float* src;
    int off;
    float scl = 1.f;
    if (i < 36864)       { src = wqkv; off = 0;
                           if (((i >> 6) % 192) < 64) scl = QSCL; }   // q rows
    else if (i < 49152)  { src = wo;   off = 36864; }
    else if (i < 147456) { src = w1;   off = 49152; }
    else                 { src = w2;   off = 147456; }
    floatx4 v = *(const floatx4*)&src[i - off];
    f16x4 o;
    o[0] = (f16)(v[0] * scl); o[1] = (f16)(v[1] * scl);
    o[2] = (f16)(v[2] * scl); o[3] = (f16)(v[3] * scl);
    *(f16x4*)&dst[i] = o;
}

__device__ inline f16x4 pack4(float a, float b, float c, float d) {
    f16x2 lo = __builtin_bit_cast(f16x2, __builtin_amdgcn_cvt_pkrtz(a, b));
    f16x2 hi = __builtin_bit_cast(f16x2, __builtin_amdgcn_cvt_pkrtz(c, d));
    f16x4 r; r[0] = lo[0]; r[1] = lo[1]; r[2] = hi[0]; r[3] = hi[1];
    return r;
}

__device__ inline float gelu_f(float x) {
    // tanh-form gelu in exp2 domain: sigmoid(1.5958*(x+0.044715x^3)); max dev ~3e-4
    float x2 = x * x;
    float u = __builtin_fmaf(x2, 0.044715f, 1.0f);
    float xm = x * -2.302585f;           // 1.5957691 * log2(e) folded
    float z = __builtin_amdgcn_exp2f(xm * u);
    return x * __builtin_amdgcn_rcpf(1.f + z);
}

// LN with 4 threads per row: each handles 16 cols, combine via shfl_xor(1),(2)
__device__ inline void ln_row_q(const f16* buf, f16* dst, int row, int q4,
                                const float* g, const float* bb) {
    float v[16];
    float sum = 0.f, sq = 0.f;
    int c0 = q4 * 16;
#pragma unroll
    for (int kv = 0; kv < 2; ++kv) {
        f16x8 x8 = *(const f16x8*)&buf[sw64(row, c0 + kv * 8)];
#pragma unroll
        for (int e = 0; e < 8; ++e) {
            float f = (float)x8[e];
            v[kv * 8 + e] = f;
            sum += f;
            sq += f * f;
        }
    }
    sum += __shfl_xor(sum, 1, 64);
    sq += __shfl_xor(sq, 1, 64);
    sum += __shfl_xor(sum, 2, 64);
    sq += __shfl_xor(sq, 2, 64);
    float mean = sum * (1.f / 64.f);
    float var = sq * (1.f / 64.f) - mean * mean;
    float rs = rsqrtf(var + 1e-5f);
#pragma unroll
    for (int kv = 0; kv < 4; ++kv) {
        floatx4 g4 = *(const floatx4*)&g[c0 + kv * 4];
        floatx4 b4 = *(const floatx4*)&bb[c0 + kv * 4];
        *(f16x4*)&dst[sw64(row, c0 + kv * 4)] =
            pack4((v[kv * 4 + 0] - mean) * rs * g4[0] + b4[0],
                  (v[kv * 4 + 1] - mean) * rs * g4[1] + b4[1],
                  (v[kv * 4 + 2] - mean) * rs * g4[2] + b4[2],
                  (v[kv * 4 + 3] - mean) * rs * g4[3] + b4[3]);
    }
}

__global__ __launch_bounds__(256, 6) void fused_tfm_kernel(Params p) {
    // LDS: 4 * 3072 f16 = 24576 B -> 6 blocks/CU (24 waves/CU)
    __shared__ __align__(16) f16 xlds[BUF];          // x; rows 35-47 stay zero
    __shared__ __align__(16) f16 scratch[3 * BUF];   // q|k|vT, then h / y / y2

    f16* qbuf = scratch;
    f16* kbuf = scratch + BUF;
    f16* vbuf = scratch + 2 * BUF;       // vT[64][40] during attn (2560); linv floats at +2560
    f16* hbuf = scratch;                 // FF h-chunk: 48x128 swizzled = 6144 elems (q|k overlay)

    const int tid = threadIdx.x;
    const int lane = tid & 63;
    const int w = tid >> 6;
    const int l15 = lane & 15;
    const int quad = lane >> 4;
    const int b = blockIdx.x;            // ONE item per block

    // ---------- build x in LDS (f16, swizzled) ----------
    for (int idx = tid; idx < S * 64; idx += 256) {
        int r = idx >> 6, d = idx & 63;
        float v;
        if (r == 0) {
            v = p.cls[d];
        } else if (r <= 24) {
            int s = r - 1;
            v = p.tokpos[s * 64 + d] + p.traits[b * 48 + s * 2] * p.traitW[d * 2]
                + p.traits[b * 48 + s * 2 + 1] * p.traitW[d * 2 + 1]
                + p.relg[b * 24 + s] * p.intentW[d];
        } else {
            v = p.mem[b * 640 + (r - 25) * 64 + d];
        }
        xlds[sw64(r, d)] = (f16)v;
    }
    for (int idx = tid; idx < (RP - S) * 64; idx += 256) {
        int r = S + (idx >> 6), d = idx & 63;
        xlds[sw64(r, d)] = (f16)0.f;
    }
    __syncthreads();

    // ---------- layers ----------
#pragma unroll 1
    for (int l = 0; l < NL; ++l) {
        const f16* Wqkv_l = p.Wqkv + l * 192 * 64;
        const float* bqkv_l = p.bqkv + l * 192;
        const f16* Wo_l = p.Wo + l * 64 * 64;
        const float* bo_l = p.bo + l * 64;
        const float* ln1g_l = p.ln1g + l * 64;
        const float* ln1b_l = p.ln1b + l * 64;
        const f16* W1_l = p.W1 + l * 512 * 64;
        const float* b1_l = p.b1 + l * 512;
        const f16* W2_l = p.W2 + l * 64 * 512;
        const float* b2_l = p.b2 + l * 64;
        const float* ln2g_l = p.ln2g + l * 64;
        const float* ln2b_l = p.ln2b + l * 64;

        // ===== QKV GEMM (swapped D^T). Wq pre-scaled by QSCL; v stored transposed =====
        {
            f16x8 xb[MT][2];
#pragma unroll
            for (int m = 0; m < MT; ++m)
#pragma unroll
                for (int kf = 0; kf < 2; ++kf)
                    xb[m][kf] = *(const f16x8*)&xlds[sw64(m * 16 + l15, kf * 32 + quad * 8)];
#pragma unroll
            for (int nt = w; nt < 12; nt += 4) {
                f16x8 wf0 = *(const f16x8*)&Wqkv_l[(nt * 16 + l15) * 64 + quad * 8];
                f16x8 wf1 = *(const f16x8*)&Wqkv_l[(nt * 16 + l15) * 64 + 32 + quad * 8];
                floatx4 bias4 = *(const floatx4*)&bqkv_l[nt * 16 + quad * 4];
                floatx4 acc[MT];
                PRIO1();
#pragma unroll
                for (int m = 0; m < MT; ++m) {
                    acc[m] = {0.f, 0.f, 0.f, 0.f};
                    acc[m] = MFMA(wf0, xb[m][0], acc[m]);
                    acc[m] = MFMA(wf1, xb[m][1], acc[m]);
                }
                PRIO0();
                if (nt < 4) {
                    int oc = nt * 16 + quad * 4;
                    floatx4 bq = bias4 * QSCL;   // bias scaled to match pre-scaled Wq
#pragma unroll
                    for (int m = 0; m < MT; ++m) {
                        int row = m * 16 + l15;
                        *(f16x4*)&qbuf[sw64(row, oc)] =
                            pack4(acc[m][0] + bq[0], acc[m][1] + bq[1],
                                  acc[m][2] + bq[2], acc[m][3] + bq[3]);
                    }
                } else if (nt < 8) {
                    int oc = (nt - 4) * 16 + quad * 4;
#pragma unroll
                    for (int m = 0; m < MT; ++m) {
                        int row = m * 16 + l15;
                        *(f16x4*)&kbuf[sw64(row, oc)] =
                            pack4(acc[m][0] + bias4[0], acc[m][1] + bias4[1],
                                  acc[m][2] + bias4[2], acc[m][3] + bias4[3]);
                    }
                } else {
                    // vT[d][j]: row stride 40
                    int oc = (nt - 8) * 16 + quad * 4;
#pragma unroll
                    for (int m = 0; m < MT; ++m) {
                        int row = m * 16 + l15;
                        if (row < S) {
                            f16* vp = vbuf + oc * 40 + row;
                            vp[0]   = (f16)(acc[m][0] + bias4[0]);
                            vp[40]  = (f16)(acc[m][1] + bias4[1]);
                            vp[80]  = (f16)(acc[m][2] + bias4[2]);
                            vp[120] = (f16)(acc[m][3] + bias4[3]);
                        }
                    }
                }
            }
            // zero vT col 35 (read by the clamped jt=2 tail frag; must be finite)
            if (tid < 64) vbuf[tid * 40 + 35] = (f16)0.f;
        }
        __syncthreads();

        // Wo weight/bias loads: global-only deps, latency hides under attention
        f16x8 wo_f0 = *(const f16x8*)&Wo_l[(w * 16 + l15) * 64 + quad * 8];
        f16x8 wo_f1 = *(const f16x8*)&Wo_l[(w * 16 + l15) * 64 + 32 + quad * 8];
        floatx4 bo4 = *(const floatx4*)&bo_l[w * 16 + quad * 4];

        // ===== attention via 16x16x16 MFMA: 8 head jobs, 2 per wave =====
        // scores C[j,q] = MFMA(K-frag, Q-frag); exp2'd C-frag doubles as PV B-frag.
        // Normalization DEFERRED: unnormalized PV stored; 1/lsum -> linv (vbuf tail),
        // applied in the Wo epilogue (row-scale commutes with x @ Wo^T).
        {
            f16x4 z4 = {};
            floatx4 zf = {0.f, 0.f, 0.f, 0.f};
            float* linv = (float*)&vbuf[2560];   // 35 floats in vT spare tail (2560..2630)
#pragma unroll
            for (int jj = 0; jj < 2; ++jj) {
                int h = w * 2 + jj;
                int ccol = h * 8 + (quad & 1) * 4;
                f16x4 kf[3], vf[3], qf[3];
#pragma unroll
                for (int jt = 0; jt < 3; ++jt) {
                    f16x4 t = *(const f16x4*)&kbuf[sw64(jt * 16 + l15, ccol)];
                    kf[jt] = (quad >= 2) ? z4 : t;
                }
                const f16* vTb = vbuf + (h * 8 + (l15 & 7)) * 40;
                vf[0] = *(const f16x4*)&vTb[quad * 4];
                vf[1] = *(const f16x4*)&vTb[16 + quad * 4];
                vf[2] = *(const f16x4*)&vTb[32];   // clamped: tail slots have P==0
#pragma unroll
                for (int qt = 0; qt < 3; ++qt)
                    qf[qt] = *(const f16x4*)&qbuf[sw64(qt * 16 + l15, ccol)];

#pragma unroll
                for (int qt = 0; qt < 3; ++qt) {
                    PRIO1();
                    floatx4 s0 = MFMA16(kf[0], qf[qt], zf);
                    floatx4 s1 = MFMA16(kf[1], qf[qt], zf);
                    floatx4 s2 = MFMA16(kf[2], qf[qt], zf);
                    PRIO0();
                    float e[12];
                    float lsum = 0.f;
#pragma unroll
                    for (int r = 0; r < 4; ++r) {
                        e[r] = __builtin_amdgcn_exp2f(s0[r]);
                        lsum += e[r];
                    }
#pragma unroll
                    for (int r = 0; r < 4; ++r) {
                        e[4 + r] = __builtin_amdgcn_exp2f(s1[r]);
                        lsum += e[4 + r];
                    }
#pragma unroll
                    for (int r = 0; r < 4; ++r) {
                        // j = 32 + quad*4 + r must be < 35
                        float v = __builtin_amdgcn_exp2f(s2[r]);
                        v = (quad == 0 && r < 3) ? v : 0.f;
                        e[8 + r] = v;
                        lsum += v;
                    }
                    f16x4 p0 = pack4(e[0], e[1], e[2], e[3]);
                    f16x4 p1 = pack4(e[4], e[5], e[6], e[7]);
                    f16x4 p2 = pack4(e[8], e[9], e[10], e[11]);
                    floatx4 acc = {0.f, 0.f, 0.f, 0.f};
                    PRIO1();
                    acc = MFMA16(vf[0], p0, acc);
                    acc = MFMA16(vf[1], p1, acc);
                    acc = MFMA16(vf[2], p2, acc);
                    PRIO0();
                    // store unnormalized PV immediately (short chain)
                    if (quad < 2 && (qt < 2 || l15 < 3)) {
                        *(f16x4*)&qbuf[sw64(qt * 16 + l15, h * 8 + quad * 4)] =
                            pack4(acc[0], acc[1], acc[2], acc[3]);
                    }
                    // lsum reduction runs in the shadow
                    lsum += __shfl_xor(lsum, 16, 64);
                    lsum += __shfl_xor(lsum, 32, 64);
                    if (w == (h >> 1) && quad == 0 && jj == (h & 1) && (qt < 2 || l15 < 3)) {
                        if (h == 0)   // lsum identical across heads' q-rows? no: only head0 wave writes
                            linv[qt * 16 + l15] = __builtin_amdgcn_rcpf(lsum);
                    }
                }
            }
        }
        __syncthreads();

        // ===== Wo GEMM (swapped) + deferred 1/lsum + residual -> y in vbuf =====
        {
            const float* linv = (const float*)&vbuf[2560];
            f16x8 ab[MT][2];
#pragma unroll
            for (int m = 0; m < MT; ++m)
#pragma unroll
                for (int kf = 0; kf < 2; ++kf)
                    ab[m][kf] = *(const f16x8*)&qbuf[sw64(m * 16 + l15, kf * 32 + quad * 8)];
            int oc = w * 16 + quad * 4;
            floatx4 oacc[MT];
            PRIO1();
#pragma unroll
            for (int m = 0; m < MT; ++m) {
                oacc[m] = {0.f, 0.f, 0.f, 0.f};
                oacc[m] = MFMA(wo_f0, ab[m][0], oacc[m]);
                oacc[m] = MFMA(wo_f1, ab[m][1], oacc[m]);
            }
            PRIO0();
#pragma unroll
            for (int m = 0; m < MT; ++m) {
                int row = m * 16 + l15;
                if (row < S) {
                    float iv = linv[row];
                    f16x4 res = *(const f16x4*)&xlds[sw64(row, oc)];
                    *(f16x4*)&vbuf[sw64(row, oc)] =
                        pack4(oacc[m][0] * iv + bo4[0] + (float)res[0],
                              oacc[m][1] * iv + bo4[1] + (float)res[1],
                              oacc[m][2] * iv + bo4[2] + (float)res[2],
                              oacc[m][3] * iv + bo4[3] + (float)res[3]);
                }
            }
        }
        __syncthreads();

        // ===== LN1: y(vbuf) -> x =====
        if (tid < 4 * S) ln_row_q(vbuf, xlds, tid >> 2, tid & 3, ln1g_l, ln1b_l);
        __syncthreads();

        // ===== FF: 4 chunks of 128 (swapped GEMMs), W2 accumulators persistent =====
        {
            f16x8 a2[MT][2];
#pragma unroll
            for (int m = 0; m < MT; ++m)
#pragma unroll
                for (int kf = 0; kf < 2; ++kf)
                    a2[m][kf] = *(const f16x8*)&xlds[sw64(m * 16 + l15, kf * 32 + quad * 8)];
            floatx4 facc[MT];
#pragma unroll
            for (int m = 0; m < MT; ++m) facc[m] = {0.f, 0.f, 0.f, 0.f};

#pragma unroll 1
            for (int c = 0; c < 4; ++c) {
#pragma unroll
                for (int ntl = w; ntl < 8; ntl += 4) {
                    int gc = c * 128 + ntl * 16;
                    f16x8 w1f0 = *(const f16x8*)&W1_l[(gc + l15) * 64 + quad * 8];
                    f16x8 w1f1 = *(const f16x8*)&W1_l[(gc + l15) * 64 + 32 + quad * 8];
                    floatx4 b14 = *(const floatx4*)&b1_l[gc + quad * 4];
                    int oc = ntl * 16 + quad * 4;
                    floatx4 hacc[MT];
                    PRIO1();
#pragma unroll
                    for (int m = 0; m < MT; ++m) {
                        hacc[m] = {0.f, 0.f, 0.f, 0.f};
                        hacc[m] = MFMA(w1f0, a2[m][0], hacc[m]);
                        hacc[m] = MFMA(w1f1, a2[m][1], hacc[m]);
                    }
                    PRIO0();
#pragma unroll
                    for (int m = 0; m < MT; ++m) {
                        int row = m * 16 + l15;
                        *(f16x4*)&hbuf[sw128(row, oc)] =
                            pack4(gelu_f(hacc[m][0] + b14[0]), gelu_f(hacc[m][1] + b14[1]),
                                  gelu_f(hacc[m][2] + b14[2]), gelu_f(hacc[m][3] + b14[3]));
                    }
                }
                // W2 frag loads issued BEFORE the barrier: global-only deps
                f16x8 w2f[4];
#pragma unroll
                for (int kf = 0; kf < 4; ++kf)
                    w2f[kf] = *(const f16x8*)&W2_l[(w * 16 + l15) * 512 + c * 128 + kf * 32 + quad * 8];
                __syncthreads();
                PRIO1();
#pragma unroll
                for (int m = 0; m < MT; ++m) {
                    f16x8 h0 = *(const f16x8*)&hbuf[sw128(m * 16 + l15, 0 + quad * 8)];
                    f16x8 h1 = *(const f16x8*)&hbuf[sw128(m * 16 + l15, 32 + quad * 8)];
                    f16x8 h2 = *(const f16x8*)&hbuf[sw128(m * 16 + l15, 64 + quad * 8)];
                    f16x8 h3 = *(const f16x8*)&hbuf[sw128(m * 16 + l15, 96 + quad * 8)];
                    facc[m] = MFMA(w2f[0], h0, facc[m]);
                    facc[m] = MFMA(w2f[1], h1, facc[m]);
                    facc[m] = MFMA(w2f[2], h2, facc[m]);
                    facc[m] = MFMA(w2f[3], h3, facc[m]);
                }
                PRIO0();
                __syncthreads();
            }

            // y2 = ff + b2 + x -> vbuf (rows < 35 only)
            int oc = w * 16 + quad * 4;
            floatx4 b24 = *(const floatx4*)&b2_l[oc];
#pragma unroll
            for (int m = 0; m < MT; ++m) {
                int row = m * 16 + l15;
                if (row < S) {
                    f16x4 res = *(const f16x4*)&xlds[sw64(row, oc)];
                    *(f16x4*)&vbuf[sw64(row, oc)] =
                        pack4(facc[m][0] + b24[0] + (float)res[0],
                              facc[m][1] + b24[1] + (float)res[1],
                              facc[m][2] + b24[2] + (float)res[2],
                              facc[m][3] + b24[3] + (float)res[3]);
                }
            }
        }
        __syncthreads();

        // ===== LN2: y2(vbuf) -> x =====
        if (tid < 4 * S) ln_row_q(vbuf, xlds, tid >> 2, tid & 3, ln2g_l, ln2b_l);
        __syncthreads();
    }

    // ---------- head: situation = ln(x[0] @ outW^T + outb) ----------
    float* sitlds = (float*)scratch;  // scratch dead after last LN2 (barrier above)
    if (tid < 128) {
        int j = tid;
        float s = p.outb[j];
#pragma unroll
        for (int kv = 0; kv < 8; ++kv) {
            f16x8 xv = *(const f16x8*)&xlds[sw64(0, kv * 8)];
            floatx4 w0 = *(const floatx4*)&p.outW[j * 64 + kv * 8];
            floatx4 w1 = *(const floatx4*)&p.outW[j * 64 + kv * 8 + 4];
#pragma unroll
            for (int e = 0; e < 4; ++e) s += (float)xv[e] * w0[e];
#pragma unroll
            for (int e = 0; e < 4; ++e) s += (float)xv[4 + e] * w1[e];
        }
        sitlds[j] = s;
    }
    __syncthreads();

    if (w == 0) {
        float v0 = sitlds[lane];
        float v1 = sitlds[64 + lane];
        float sum = v0 + v1, sq = v0 * v0 + v1 * v1;
#pragma unroll
        for (int off = 32; off >= 1; off >>= 1) {
            sum += __shfl_xor(sum, off, 64);
            sq += __shfl_xor(sq, off, 64);
        }
        float mean = sum * (1.f / 128.f);
        float rs = rsqrtf(sq * (1.f / 128.f) - mean * mean + 1e-5f);
        __builtin_nontemporal_store((v0 - mean) * rs * p.olng[lane] + p.olnb[lane],
                                    &p.out[b * 128 + lane]);
        __builtin_nontemporal_store((v1 - mean) * rs * p.olng[64 + lane] + p.olnb[64 + lane],
                                    &p.out[b * 128 + 64 + lane]);
    }

    // situation_sequence: x rows 1..24 -> fp32
    for (int pp = tid; pp < 384; pp += 256) {
        int s = pp >> 4, dp = (pp & 15) * 4;
        f16x4 xv = *(const f16x4*)&xlds[sw64(1 + s, dp)];
        floatx4 o = {(float)xv[0], (float)xv[1], (float)xv[2], (float)xv[3]};
        __builtin_nontemporal_store(o, (floatx4*)&p.out[SEQOFF + b * 1536 + s * 64 + dp]);
    }
    // new_memory rows 0..8: passthrough of memory_context rows 1..9
    if (tid < 144) {
        int mr = tid >> 4, dp = (tid & 15) * 4;
        floatx4 v = *(const floatx4*)&p.mem[b * 640 + (1 + mr) * 64 + dp];
        __builtin_nontemporal_store(v, (floatx4*)&p.out[MEMOFF + b * 640 + mr * 64 + dp]);
    }
    // new_memory row 9: mean of x rows 1..24
    if (tid < 64) {
        int d = tid;
        float s = 0.f;
#pragma unroll
        for (int sr = 0; sr < 24; ++sr) s += (float)xlds[sw64(1 + sr, d)];
        __builtin_nontemporal_store(s * (1.f / 24.f), &p.out[MEMOFF + b * 640 + 576 + d]);
    }
}

extern "C" void kernel_launch(void* const* d_in, const int* in_sizes, int n_in,
                              void* d_out, int out_size, void* d_ws, size_t ws_size,
                              hipStream_t stream) {
    (void)in_sizes; (void)n_in; (void)out_size; (void)ws_size;

    f16* ws = (f16*)d_ws;
    hipLaunchKernelGGL(cvt_all, dim3(241), dim3(256), 0, stream,
                       (const float*)d_in[11], (const float*)d_in[13],
                       (const float*)d_in[17], (const float*)d_in[19],
                       (const int*)d_in[0], (const float*)d_in[4],
                       (const float*)d_in[5], (const float*)d_in[7],
                       (const float*)d_in[9], ws);

    Params p;
    p.tok = (const int*)d_in[0];
    p.traits = (const float*)d_in[1];
    p.relg = (const float*)d_in[2];
    p.mem = (const float*)d_in[3];
    p.temb = (const float*)d_in[4];
    p.demb = (const float*)d_in[5];
    p.traitW = (const float*)d_in[6];
    p.traitb = (const float*)d_in[7];
    p.intentW = (const float*)d_in[8];
    p.intentb = (const float*)d_in[9];
    p.cls = (const float*)d_in[10];
    p.bqkv = (const float*)d_in[12];
    p.bo = (const float*)d_in[14];
    p.ln1g = (const float*)d_in[15];
    p.ln1b = (const float*)d_in[16];
    p.b1 = (const float*)d_in[18];
    p.b2 = (const float*)d_in[20];
    p.ln2g = (const float*)d_in[21];
    p.ln2b = (const float*)d_in[22];
    p.outW = (const float*)d_in[23];
    p.outb = (const float*)d_in[24];
    p.olng = (const float*)d_in[25];
    p.olnb = (const float*)d_in[26];
    p.Wqkv = ws;                 // 36864
    p.Wo = ws + 36864;           // 12288
    p.W1 = ws + 49152;           // 98304
    p.W2 = ws + 147456;          // 98304
    p.tokpos = (const float*)(ws + TOKPOS_OFF);
    p.out = (float*)d_out;

    hipLaunchKernelGGL(fused_tfm_kernel, dim3(4096), dim3(256), 0, stream, p);
}

// Round 8
// 437.420 us; speedup vs baseline: 1.3351x; 1.3351x over previous
//
#include <hip/hip_runtime.h>

typedef _Float16 f16;
typedef _Float16 f16x2 __attribute__((ext_vector_type(2)));
typedef _Float16 f16x4 __attribute__((ext_vector_type(4)));
typedef _Float16 f16x8 __attribute__((ext_vector_type(8)));
typedef float floatx4 __attribute__((ext_vector_type(4)));

#define MFMA(a, b, c) __builtin_amdgcn_mfma_f32_16x16x32_f16((a), (b), (c), 0, 0, 0)
#define MFMA16(a, b, c) __builtin_amdgcn_mfma_f32_16x16x16f16((a), (b), (c), 0, 0, 0)
#define PRIO1() __builtin_amdgcn_s_setprio(1)
#define PRIO0() __builtin_amdgcn_s_setprio(0)

// Problem constants
constexpr int S = 35;        // 1 cls + 24 dims + 10 mem
constexpr int NH = 8;
constexpr int NL = 3;
constexpr int G = 2;         // batch items per block
constexpr int RP = 80;       // padded rows (G*35 = 70 -> 5 row-tiles)
constexpr int MT = 5;        // MFMA row-tiles
constexpr int BUF = RP * 64; // 5120 elems per swizzled 80x64 buffer
constexpr int SEQOFF = 4096 * 128;                 // 524288
constexpr int MEMOFF = SEQOFF + 4096 * 24 * 64;    // 6815744
constexpr int TOKPOS_OFF = 245760;                 // f16 elems into ws; tokpos floats live there
constexpr float QSCL = 0.51006982f;                // 1/sqrt(8) * log2(e), folded into Wq at cvt

// XOR swizzle: 8-col groups rotated by row&7 -> stride-64 rows, conflict-free patterns
__device__ __forceinline__ int sw64(int r, int c) {
    return (r << 6) + ((((c >> 3) ^ r) & 7) << 3) + (c & 7);
}
__device__ __forceinline__ int sw128(int r, int c) {
    return (r << 7) + ((((c >> 3) ^ (r & 7))) << 3) + (c & 7);
}

struct Params {
    const int* tok;
    const float *traits, *relg, *mem, *temb, *demb, *traitW, *traitb, *intentW, *intentb, *cls;
    const float *bqkv, *bo, *ln1g, *ln1b, *b1, *b2, *ln2g, *ln2b;
    const float *outW, *outb, *olng, *olnb;
    const f16 *Wqkv, *Wo, *W1, *W2;   // converted into d_ws
    const float* tokpos;              // precomputed in d_ws
    float* out;
};

// fp32->f16 weight conversion (Wq rows prescaled by QSCL) + tokpos precompute (block 240)
__global__ void cvt_all(const float* __restrict__ wqkv, const float* __restrict__ wo,
                        const float* __restrict__ w1, const float* __restrict__ w2,
                        const int* __restrict__ tok, const float* __restrict__ temb,
                        const float* __restrict__ demb, const float* __restrict__ traitb,
                        const float* __restrict__ intentb, f16* __restrict__ dst) {
    if (blockIdx.x == 240) {
        // tokpos[s][d] = mean_t temb[tok[s,t]][d] + demb[s][d] + traitb[d] + intentb[d]
        float* tp = (float*)(dst + TOKPOS_OFF);
        for (int idx = threadIdx.x; idx < 24 * 64; idx += 256) {
            int s = idx >> 6, d = idx & 63;
            float a = 0.f;
#pragma unroll
            for (int t = 0; t < 8; ++t) a += temb[tok[s * 8 + t] * 64 + d];
            tp[idx] = a * 0.125f + demb[idx] + traitb[d] + intentb[d];
        }
        return;
    }
    int i = (blockIdx.x * 256 + threadIdx.x) * 4;
    const float* src;
    int off;
    float scl = 1.f;
    if (i < 36864)       { src = wqkv; off = 0;
                           if (((i >> 6) % 192) < 64) scl = QSCL; }   // q rows
    else if (i < 49152)  { src = wo;   off = 36864; }
    else if (i < 147456) { src = w1;   off = 49152; }
    else                 { src = w2;   off = 147456; }
    floatx4 v = *(const floatx4*)&src[i - off];
    f16x4 o;
    o[0] = (f16)(v[0] * scl); o[1] = (f16)(v[1] * scl);
    o[2] = (f16)(v[2] * scl); o[3] = (f16)(v[3] * scl);
    *(f16x4*)&dst[i] = o;
}

__device__ inline f16x4 pack4(float a, float b, float c, float d) {
    f16x2 lo = __builtin_bit_cast(f16x2, __builtin_amdgcn_cvt_pkrtz(a, b));
    f16x2 hi = __builtin_bit_cast(f16x2, __builtin_amdgcn_cvt_pkrtz(c, d));
    f16x4 r; r[0] = lo[0]; r[1] = lo[1]; r[2] = hi[0]; r[3] = hi[1];
    return r;
}

// f16 transcendentals (VOP1, gfx9+)
__device__ inline f16 exp2h(f16 x) { f16 r; asm("v_exp_f16 %0, %1" : "=v"(r) : "v"(x)); return r; }
__device__ inline f16 rcph(f16 x)  { f16 r; asm("v_rcp_f16 %0, %1" : "=v"(r) : "v"(x)); return r; }

// packed-f16 gelu: x * sigmoid(1.5958*(x+0.044715x^3)) in exp2 domain.
// Tail exactness: arg >= +16 -> exp2h = +inf -> rcp = 0 -> out = -0 (correct);
// arg <= -14 -> z = 0 -> out = x (correct).
__device__ inline f16x2 gelu_pk(f16x2 x) {
    const f16 k044 = (f16)0.044715f;
    const f16 kone = (f16)1.f;
    const f16 km   = (f16)-2.302585f;   // 1.5957691 * log2(e) folded
    f16x2 c044 = {k044, k044};
    f16x2 one  = {kone, kone};
    f16x2 cm   = {km, km};
    f16x2 x2 = x * x;
    f16x2 u  = x2 * c044 + one;
    f16x2 arg = (x * u) * cm;
    f16x2 z;
    z[0] = exp2h(arg[0]);
    z[1] = exp2h(arg[1]);
    f16x2 d = z + one;
    f16x2 r;
    r[0] = rcph(d[0]);
    r[1] = rcph(d[1]);
    return x * r;
}

// LN with 2 threads per row: each handles 32 cols, combine sums via shfl_xor(1)
__device__ inline void ln_row_half(const f16* buf, f16* dst, int row, int half,
                                   const float* g, const float* bb) {
    float v[32];
    float sum = 0.f, sq = 0.f;
    int c0 = half * 32;
#pragma unroll
    for (int kv = 0; kv < 4; ++kv) {
        f16x8 x8 = *(const f16x8*)&buf[sw64(row, c0 + kv * 8)];
#pragma unroll
        for (int e = 0; e < 8; ++e) {
            float f = (float)x8[e];
            v[kv * 8 + e] = f;
            sum += f;
            sq += f * f;
        }
    }
    sum += __shfl_xor(sum, 1, 64);
    sq += __shfl_xor(sq, 1, 64);
    float mean = sum * (1.f / 64.f);
    float var = sq * (1.f / 64.f) - mean * mean;
    float rs = rsqrtf(var + 1e-5f);
#pragma unroll
    for (int kv = 0; kv < 8; ++kv) {
        floatx4 g4 = *(const floatx4*)&g[c0 + kv * 4];
        floatx4 b4 = *(const floatx4*)&bb[c0 + kv * 4];
        *(f16x4*)&dst[sw64(row, c0 + kv * 4)] =
            pack4((v[kv * 4 + 0] - mean) * rs * g4[0] + b4[0],
                  (v[kv * 4 + 1] - mean) * rs * g4[1] + b4[1],
                  (v[kv * 4 + 2] - mean) * rs * g4[2] + b4[2],
                  (v[kv * 4 + 3] - mean) * rs * g4[3] + b4[3]);
    }
}

__global__ __launch_bounds__(256, 4) void fused_tfm_kernel(Params p) {
    // LDS: (5120 + 15360) f16 = 40960 B -> exactly 4 blocks/CU
    __shared__ __align__(16) f16 xlds[BUF];          // x (residual stream); pad rows 70-79 host linv
    __shared__ __align__(16) f16 scratch[3 * BUF];   // q|k|vT, then h / y / y2; head reuses as float

    f16* qbuf = scratch;
    f16* kbuf = scratch + BUF;
    f16* vbuf = scratch + 2 * BUF;       // vT[2][64][40] during attn; y / y2 home after
    f16* hbuf = scratch;                 // FF h-chunk: 80x128 swizzled, overlays dead q|k

    const int tid = threadIdx.x;
    const int lane = tid & 63;
    const int w = tid >> 6;
    const int l15 = lane & 15;
    const int quad = lane >> 4;
    const int b0 = blockIdx.x * G;

    // ---------- build x in LDS (f16, swizzled) ----------
    for (int idx = tid; idx < G * S * 64; idx += 256) {
        int i = idx / (S * 64);
        int rem = idx - i * S * 64;
        int r = rem >> 6, d = rem & 63;
        int b = b0 + i;
        float v;
        if (r == 0) {
            v = p.cls[d];
        } else if (r <= 24) {
            int s = r - 1;
            v = p.tokpos[s * 64 + d] + p.traits[b * 48 + s * 2] * p.traitW[d * 2]
                + p.traits[b * 48 + s * 2 + 1] * p.traitW[d * 2 + 1]
                + p.relg[b * 24 + s] * p.intentW[d];
        } else {
            v = p.mem[b * 640 + (r - 25) * 64 + d];
        }
        xlds[sw64(i * S + r, d)] = (f16)v;
    }
    for (int idx = tid; idx < (RP - G * S) * 64; idx += 256) {
        int r = G * S + (idx >> 6), d = idx & 63;
        xlds[sw64(r, d)] = (f16)0.f;
    }
    __syncthreads();

    // ---------- layers ----------
#pragma unroll 1
    for (int l = 0; l < NL; ++l) {
        const f16* Wqkv_l = p.Wqkv + l * 192 * 64;
        const float* bqkv_l = p.bqkv + l * 192;
        const f16* Wo_l = p.Wo + l * 64 * 64;
        const float* bo_l = p.bo + l * 64;
        const float* ln1g_l = p.ln1g + l * 64;
        const float* ln1b_l = p.ln1b + l * 64;
        const f16* W1_l = p.W1 + l * 512 * 64;
        const float* b1_l = p.b1 + l * 512;
        const f16* W2_l = p.W2 + l * 64 * 512;
        const float* b2_l = p.b2 + l * 64;
        const float* ln2g_l = p.ln2g + l * 64;
        const float* ln2b_l = p.ln2b + l * 64;

        // ===== QKV GEMM (swapped D^T). Wq pre-scaled by QSCL; v stored transposed =====
        {
            f16x8 xb[MT][2];
#pragma unroll
            for (int m = 0; m < MT; ++m)
#pragma unroll
                for (int kf = 0; kf < 2; ++kf)
                    xb[m][kf] = *(const f16x8*)&xlds[sw64(m * 16 + l15, kf * 32 + quad * 8)];
#pragma unroll
            for (int nt = w; nt < 12; nt += 4) {
                f16x8 wf0 = *(const f16x8*)&Wqkv_l[(nt * 16 + l15) * 64 + quad * 8];
                f16x8 wf1 = *(const f16x8*)&Wqkv_l[(nt * 16 + l15) * 64 + 32 + quad * 8];
                floatx4 bias4 = *(const floatx4*)&bqkv_l[nt * 16 + quad * 4];
                floatx4 acc[MT];
                PRIO1();
#pragma unroll
                for (int m = 0; m < MT; ++m) {
                    acc[m] = {0.f, 0.f, 0.f, 0.f};
                    acc[m] = MFMA(wf0, xb[m][0], acc[m]);
                    acc[m] = MFMA(wf1, xb[m][1], acc[m]);
                }
                PRIO0();
                if (nt < 4) {
                    int oc = nt * 16 + quad * 4;
                    floatx4 bq = bias4 * QSCL;   // bias scaled to match pre-scaled Wq
#pragma unroll
                    for (int m = 0; m < MT; ++m) {
                        int row = m * 16 + l15;
                        *(f16x4*)&qbuf[sw64(row, oc)] =
                            pack4(acc[m][0] + bq[0], acc[m][1] + bq[1],
                                  acc[m][2] + bq[2], acc[m][3] + bq[3]);
                    }
                } else if (nt < 8) {
                    int oc = (nt - 4) * 16 + quad * 4;
#pragma unroll
                    for (int m = 0; m < MT; ++m) {
                        int row = m * 16 + l15;
                        *(f16x4*)&kbuf[sw64(row, oc)] =
                            pack4(acc[m][0] + bias4[0], acc[m][1] + bias4[1],
                                  acc[m][2] + bias4[2], acc[m][3] + bias4[3]);
                    }
                } else {
                    // vT[item][d][j]: row stride 40, per-item stride 2560
                    int oc = (nt - 8) * 16 + quad * 4;
#pragma unroll
                    for (int m = 0; m < MT; ++m) {
                        int row = m * 16 + l15;
                        if (row < 70) {
                            int ii = row >= 35 ? 1 : 0;
                            f16* vp = vbuf + ii * 2560 + oc * 40 + (row - ii * 35);
                            vp[0]   = (f16)(acc[m][0] + bias4[0]);
                            vp[40]  = (f16)(acc[m][1] + bias4[1]);
                            vp[80]  = (f16)(acc[m][2] + bias4[2]);
                            vp[120] = (f16)(acc[m][3] + bias4[3]);
                        }
                    }
                }
            }
            // zero vT col 35 (read by the clamped jt=2 tail frag; must be finite)
            if (tid < 128) vbuf[(tid >> 6) * 2560 + (tid & 63) * 40 + 35] = (f16)0.f;
        }
        __syncthreads();

        // Wo weight/bias loads: global-only deps, latency hides under attention
        f16x8 wo_f0 = *(const f16x8*)&Wo_l[(w * 16 + l15) * 64 + quad * 8];
        f16x8 wo_f1 = *(const f16x8*)&Wo_l[(w * 16 + l15) * 64 + 32 + quad * 8];
        floatx4 bo4 = *(const floatx4*)&bo_l[w * 16 + quad * 4];

        // ===== attention via 16x16x16 MFMA: 16 (item,head) jobs, 4 per wave =====
        // scores C[j,q] = MFMA(K-frag, Q-frag); exp2'd C-frag doubles as PV B-frag.
        // Normalization DEFERRED: store unnormalized PV; 1/lsum -> linv (xlds pad rows),
        // applied in the Wo epilogue (row-scale commutes with x @ Wo^T).
        {
            f16x4 z4 = {};
            floatx4 zf = {0.f, 0.f, 0.f, 0.f};
            float* linv = (float*)&xlds[70 * 64];   // 80 floats in dead pad rows
#pragma unroll 2
            for (int jj = 0; jj < 4; ++jj) {
                int job = w * 4 + jj;
                int i = job >> 3;
                int h = job & 7;
                int rbase = i * S;
                int ccol = h * 8 + (quad & 1) * 4;
                f16x4 kf[3], vf[3], qf[3];
#pragma unroll
                for (int jt = 0; jt < 3; ++jt) {
                    f16x4 t = *(const f16x4*)&kbuf[sw64(rbase + jt * 16 + l15, ccol)];
                    kf[jt] = (quad >= 2) ? z4 : t;
                }
                const f16* vTb = vbuf + i * 2560 + (h * 8 + (l15 & 7)) * 40;
                vf[0] = *(const f16x4*)&vTb[quad * 4];
                vf[1] = *(const f16x4*)&vTb[16 + quad * 4];
                vf[2] = *(const f16x4*)&vTb[32];   // clamped: tail slots have P==0
#pragma unroll
                for (int qt = 0; qt < 3; ++qt)
                    qf[qt] = *(const f16x4*)&qbuf[sw64(rbase + qt * 16 + l15, ccol)];

#pragma unroll
                for (int qt = 0; qt < 3; ++qt) {
                    PRIO1();
                    floatx4 s0 = MFMA16(kf[0], qf[qt], zf);
                    floatx4 s1 = MFMA16(kf[1], qf[qt], zf);
                    floatx4 s2 = MFMA16(kf[2], qf[qt], zf);
                    PRIO0();
                    float e[12];
                    float lsum = 0.f;
#pragma unroll
                    for (int r = 0; r < 4; ++r) {
                        e[r] = __builtin_amdgcn_exp2f(s0[r]);
                        lsum += e[r];
                    }
#pragma unroll
                    for (int r = 0; r < 4; ++r) {
                        e[4 + r] = __builtin_amdgcn_exp2f(s1[r]);
                        lsum += e[4 + r];
                    }
#pragma unroll
                    for (int r = 0; r < 4; ++r) {
                        // j = 32 + quad*4 + r must be < 35
                        float v = __builtin_amdgcn_exp2f(s2[r]);
                        v = (quad == 0 && r < 3) ? v : 0.f;
                        e[8 + r] = v;
                        lsum += v;
                    }
                    f16x4 p0 = pack4(e[0], e[1], e[2], e[3]);
                    f16x4 p1 = pack4(e[4], e[5], e[6], e[7]);
                    f16x4 p2 = pack4(e[8], e[9], e[10], e[11]);
                    floatx4 acc = {0.f, 0.f, 0.f, 0.f};
                    PRIO1();
                    acc = MFMA16(vf[0], p0, acc);
                    acc = MFMA16(vf[1], p1, acc);
                    acc = MFMA16(vf[2], p2, acc);
                    PRIO0();
                    // store unnormalized PV immediately (short chain)
                    if (quad < 2 && (qt < 2 || l15 < 3)) {
                        *(f16x4*)&qbuf[sw64(rbase + qt * 16 + l15, h * 8 + quad * 4)] =
                            pack4(acc[0], acc[1], acc[2], acc[3]);
                    }
                    // lsum reduction runs in the shadow
                    lsum += __shfl_xor(lsum, 16, 64);
                    lsum += __shfl_xor(lsum, 32, 64);
                    if (quad == 0 && (qt < 2 || l15 < 3))
                        linv[rbase + qt * 16 + l15] = __builtin_amdgcn_rcpf(lsum);
                }
            }
        }
        __syncthreads();

        // ===== Wo GEMM (swapped) + deferred 1/lsum + residual -> y in vbuf =====
        {
            const float* linv = (const float*)&xlds[70 * 64];
            f16x8 ab[MT][2];
#pragma unroll
            for (int m = 0; m < MT; ++m)
#pragma unroll
                for (int kf = 0; kf < 2; ++kf)
                    ab[m][kf] = *(const f16x8*)&qbuf[sw64(m * 16 + l15, kf * 32 + quad * 8)];
            int oc = w * 16 + quad * 4;
            floatx4 oacc[MT];
            PRIO1();
#pragma unroll
            for (int m = 0; m < MT; ++m) {
                oacc[m] = {0.f, 0.f, 0.f, 0.f};
                oacc[m] = MFMA(wo_f0, ab[m][0], oacc[m]);
                oacc[m] = MFMA(wo_f1, ab[m][1], oacc[m]);
            }
            PRIO0();
#pragma unroll
            for (int m = 0; m < MT; ++m) {
                int row = m * 16 + l15;
                float iv = linv[row];
                f16x4 res = *(const f16x4*)&xlds[sw64(row, oc)];
                *(f16x4*)&vbuf[sw64(row, oc)] =
                    pack4(oacc[m][0] * iv + bo4[0] + (float)res[0],
                          oacc[m][1] * iv + bo4[1] + (float)res[1],
                          oacc[m][2] * iv + bo4[2] + (float)res[2],
                          oacc[m][3] * iv + bo4[3] + (float)res[3]);
            }
        }
        __syncthreads();

        // ===== LN1: y(vbuf) -> x =====
        if (tid < 2 * G * S) ln_row_half(vbuf, xlds, tid >> 1, tid & 1, ln1g_l, ln1b_l);
        __syncthreads();

        // ===== FF: 4 chunks of 128 (swapped GEMMs), W2 accumulators persistent =====
        {
            f16x8 a2[MT][2];
#pragma unroll
            for (int m = 0; m < MT; ++m)
#pragma unroll
                for (int kf = 0; kf < 2; ++kf)
                    a2[m][kf] = *(const f16x8*)&xlds[sw64(m * 16 + l15, kf * 32 + quad * 8)];
            floatx4 facc[MT];
#pragma unroll
            for (int m = 0; m < MT; ++m) facc[m] = {0.f, 0.f, 0.f, 0.f};

#pragma unroll 1
            for (int c = 0; c < 4; ++c) {
#pragma unroll
                for (int ntl = w; ntl < 8; ntl += 4) {
                    int gc = c * 128 + ntl * 16;
                    f16x8 w1f0 = *(const f16x8*)&W1_l[(gc + l15) * 64 + quad * 8];
                    f16x8 w1f1 = *(const f16x8*)&W1_l[(gc + l15) * 64 + 32 + quad * 8];
                    floatx4 b14 = *(const floatx4*)&b1_l[gc + quad * 4];
                    int oc = ntl * 16 + quad * 4;
                    floatx4 hacc[MT];
                    PRIO1();
#pragma unroll
                    for (int m = 0; m < MT; ++m) {
                        hacc[m] = {0.f, 0.f, 0.f, 0.f};
                        hacc[m] = MFMA(w1f0, a2[m][0], hacc[m]);
                        hacc[m] = MFMA(w1f1, a2[m][1], hacc[m]);
                    }
                    PRIO0();
#pragma unroll
                    for (int m = 0; m < MT; ++m) {
                        int row = m * 16 + l15;
                        f16x2 lo = __builtin_bit_cast(f16x2,
                            __builtin_amdgcn_cvt_pkrtz(hacc[m][0] + b14[0], hacc[m][1] + b14[1]));
                        f16x2 hi = __builtin_bit_cast(f16x2,
                            __builtin_amdgcn_cvt_pkrtz(hacc[m][2] + b14[2], hacc[m][3] + b14[3]));
                        lo = gelu_pk(lo);
                        hi = gelu_pk(hi);
                        f16x4 hv;
                        hv[0] = lo[0]; hv[1] = lo[1]; hv[2] = hi[0]; hv[3] = hi[1];
                        *(f16x4*)&hbuf[sw128(row, oc)] = hv;
                    }
                }
                // W2 frag loads issued BEFORE the barrier: global-only deps
                f16x8 w2f[4];
#pragma unroll
                for (int kf = 0; kf < 4; ++kf)
                    w2f[kf] = *(const f16x8*)&W2_l[(w * 16 + l15) * 512 + c * 128 + kf * 32 + quad * 8];
                __syncthreads();
                PRIO1();
#pragma unroll
                for (int m = 0; m < MT; ++m) {
                    f16x8 h0 = *(const f16x8*)&hbuf[sw128(m * 16 + l15, 0 + quad * 8)];
                    f16x8 h1 = *(const f16x8*)&hbuf[sw128(m * 16 + l15, 32 + quad * 8)];
                    f16x8 h2 = *(const f16x8*)&hbuf[sw128(m * 16 + l15, 64 + quad * 8)];
                    f16x8 h3 = *(const f16x8*)&hbuf[sw128(m * 16 + l15, 96 + quad * 8)];
                    facc[m] = MFMA(w2f[0], h0, facc[m]);
                    facc[m] = MFMA(w2f[1], h1, facc[m]);
                    facc[m] = MFMA(w2f[2], h2, facc[m]);
                    facc[m] = MFMA(w2f[3], h3, facc[m]);
                }
                PRIO0();
                __syncthreads();
            }

            // y2 = ff + b2 + x -> vbuf
            int oc = w * 16 + quad * 4;
            floatx4 b24 = *(const floatx4*)&b2_l[oc];
#pragma unroll
            for (int m = 0; m < MT; ++m) {
                int row = m * 16 + l15;
                f16x4 res = *(const f16x4*)&xlds[sw64(row, oc)];
                *(f16x4*)&vbuf[sw64(row, oc)] =
                    pack4(facc[m][0] + b24[0] + (float)res[0],
                          facc[m][1] + b24[1] + (float)res[1],
                          facc[m][2] + b24[2] + (float)res[2],
                          facc[m][3] + b24[3] + (float)res[3]);
            }
        }
        __syncthreads();

        // ===== LN2: y2(vbuf) -> x =====
        if (tid < 2 * G * S) ln_row_half(vbuf, xlds, tid >> 1, tid & 1, ln2g_l, ln2b_l);
        __syncthreads();
    }

    // ---------- head: situation = ln(x[:,0] @ outW^T + outb) ----------
    float* sitlds = (float*)scratch;  // scratch dead after last LN2 (barrier above)
    {
        int i = tid >> 7, j = tid & 127;
        float s = p.outb[j];
#pragma unroll
        for (int kv = 0; kv < 8; ++kv) {
            f16x8 xv = *(const f16x8*)&xlds[sw64(i * S, kv * 8)];
            floatx4 w0 = *(const floatx4*)&p.outW[j * 64 + kv * 8];
            floatx4 w1 = *(const floatx4*)&p.outW[j * 64 + kv * 8 + 4];
#pragma unroll
            for (int e = 0; e < 4; ++e) s += (float)xv[e] * w0[e];
#pragma unroll
            for (int e = 0; e < 4; ++e) s += (float)xv[4 + e] * w1[e];
        }
        sitlds[i * 128 + j] = s;
    }
    __syncthreads();

    if (w < 2) {
        int i = w;
        float v0 = sitlds[i * 128 + lane];
        float v1 = sitlds[i * 128 + 64 + lane];
        float sum = v0 + v1, sq = v0 * v0 + v1 * v1;
#pragma unroll
        for (int off = 32; off >= 1; off >>= 1) {
            sum += __shfl_xor(sum, off, 64);
            sq += __shfl_xor(sq, off, 64);
        }
        float mean = sum * (1.f / 128.f);
        float rs = rsqrtf(sq * (1.f / 128.f) - mean * mean + 1e-5f);
        int b = b0 + i;
        p.out[b * 128 + lane] = (v0 - mean) * rs * p.olng[lane] + p.olnb[lane];
        p.out[b * 128 + 64 + lane] = (v1 - mean) * rs * p.olng[64 + lane] + p.olnb[64 + lane];
    }

    // situation_sequence: x rows 1..24 -> fp32
    for (int pp = tid; pp < G * 384; pp += 256) {
        int i = pp / 384;
        int q = pp - i * 384;
        int s = q >> 4, dp = (q & 15) * 4;
        int b = b0 + i;
        f16x4 xv = *(const f16x4*)&xlds[sw64(i * S + 1 + s, dp)];
        floatx4 o = {(float)xv[0], (float)xv[1], (float)xv[2], (float)xv[3]};
        *(floatx4*)&p.out[SEQOFF + b * 1536 + s * 64 + dp] = o;
    }
    // new_memory rows 0..8: passthrough of memory_context rows 1..9
    for (int pp = tid; pp < G * 144; pp += 256) {
        int i = pp / 144;
        int q = pp - i * 144;
        int mr = q >> 4, dp = (q & 15) * 4;
        int b = b0 + i;
        floatx4 v = *(const floatx4*)&p.mem[b * 640 + (1 + mr) * 64 + dp];
        *(floatx4*)&p.out[MEMOFF + b * 640 + mr * 64 + dp] = v;
    }
    // new_memory row 9: mean of x rows 1..24
    if (tid < G * 64) {
        int i = tid >> 6, d = tid & 63;
        float s = 0.f;
#pragma unroll
        for (int sr = 0; sr < 24; ++sr) s += (float)xlds[sw64(i * S + 1 + sr, d)];
        p.out[MEMOFF + (b0 + i) * 640 + 576 + d] = s * (1.f / 24.f);
    }
}

extern "C" void kernel_launch(void* const* d_in, const int* in_sizes, int n_in,
                              void* d_out, int out_size, void* d_ws, size_t ws_size,
                              hipStream_t stream) {
    (void)in_sizes; (void)n_in; (void)out_size; (void)ws_size;

    f16* ws = (f16*)d_ws;
    hipLaunchKernelGGL(cvt_all, dim3(241), dim3(256), 0, stream,
                       (const float*)d_in[11], (const float*)d_in[13],
                       (const float*)d_in[17], (const float*)d_in[19],
                       (const int*)d_in[0], (const float*)d_in[4],
                       (const float*)d_in[5], (const float*)d_in[7],
                       (const float*)d_in[9], ws);

    Params p;
    p.tok = (const int*)d_in[0];
    p.traits = (const float*)d_in[1];
    p.relg = (const float*)d_in[2];
    p.mem = (const float*)d_in[3];
    p.temb = (const float*)d_in[4];
    p.demb = (const float*)d_in[5];
    p.traitW = (const float*)d_in[6];
    p.traitb = (const float*)d_in[7];
    p.intentW = (const float*)d_in[8];
    p.intentb = (const float*)d_in[9];
    p.cls = (const float*)d_in[10];
    p.bqkv = (const float*)d_in[12];
    p.bo = (const float*)d_in[14];
    p.ln1g = (const float*)d_in[15];
    p.ln1b = (const float*)d_in[16];
    p.b1 = (const float*)d_in[18];
    p.b2 = (const float*)d_in[20];
    p.ln2g = (const float*)d_in[21];
    p.ln2b = (const float*)d_in[22];
    p.outW = (const float*)d_in[23];
    p.outb = (const float*)d_in[24];
    p.olng = (const float*)d_in[25];
    p.olnb = (const float*)d_in[26];
    p.Wqkv = ws;                 // 36864
    p.Wo = ws + 36864;           // 12288
    p.W1 = ws + 49152;           // 98304
    p.W2 = ws + 147456;          // 98304
    p.tokpos = (const float*)(ws + TOKPOS_OFF);
    p.out = (float*)d_out;

    hipLaunchKernelGGL(fused_tfm_kernel, dim3(4096 / G), dim3(256), 0, stream, p);
}

// Round 9
// 433.533 us; speedup vs baseline: 1.3471x; 1.0090x over previous
//
#include <hip/hip_runtime.h>

typedef _Float16 f16;
typedef _Float16 f16x2 __attribute__((ext_vector_type(2)));
typedef _Float16 f16x4 __attribute__((ext_vector_type(4)));
typedef _Float16 f16x8 __attribute__((ext_vector_type(8)));
typedef float floatx4 __attribute__((ext_vector_type(4)));
typedef float floatx2 __attribute__((ext_vector_type(2)));

#define MFMA(a, b, c) __builtin_amdgcn_mfma_f32_16x16x32_f16((a), (b), (c), 0, 0, 0)
#define MFMA16(a, b, c) __builtin_amdgcn_mfma_f32_16x16x16f16((a), (b), (c), 0, 0, 0)
#define PRIO1() __builtin_amdgcn_s_setprio(1)
#define PRIO0() __builtin_amdgcn_s_setprio(0)

// Problem constants
constexpr int S = 35;        // 1 cls + 24 dims + 10 mem
constexpr int NH = 8;
constexpr int NL = 3;
constexpr int G = 2;         // batch items per block
constexpr int RP = 80;       // padded rows (G*35 = 70 -> 5 row-tiles)
constexpr int MT = 5;        // MFMA row-tiles
constexpr int BUF = RP * 64; // 5120 elems per swizzled 80x64 buffer
constexpr int SEQOFF = 4096 * 128;                 // 524288
constexpr int MEMOFF = SEQOFF + 4096 * 24 * 64;    // 6815744
constexpr int TOKPOS_OFF = 245760;                 // f16 elems into ws; tokpos floats live there
constexpr float QSCL = 0.51006982f;                // 1/sqrt(8) * log2(e), folded into Wq at cvt

// XOR swizzle: 8-col groups rotated by row&7 -> stride-64 rows, conflict-free patterns
__device__ __forceinline__ int sw64(int r, int c) {
    return (r << 6) + ((((c >> 3) ^ r) & 7) << 3) + (c & 7);
}
__device__ __forceinline__ int sw128(int r, int c) {
    return (r << 7) + ((((c >> 3) ^ (r & 7))) << 3) + (c & 7);
}

struct Params {
    const int* tok;
    const float *traits, *relg, *mem, *temb, *demb, *traitW, *traitb, *intentW, *intentb, *cls;
    const float *bqkv, *bo, *ln1g, *ln1b, *b1, *b2, *ln2g, *ln2b;
    const float *outW, *outb, *olng, *olnb;
    const f16 *Wqkv, *Wo, *W1, *W2;   // converted into d_ws
    const float* tokpos;              // precomputed in d_ws
    float* out;
};

// fp32->f16 weight conversion (Wq rows prescaled by QSCL) + tokpos precompute (block 240)
__global__ void cvt_all(const float* __restrict__ wqkv, const float* __restrict__ wo,
                        const float* __restrict__ w1, const float* __restrict__ w2,
                        const int* __restrict__ tok, const float* __restrict__ temb,
                        const float* __restrict__ demb, const float* __restrict__ traitb,
                        const float* __restrict__ intentb, f16* __restrict__ dst) {
    if (blockIdx.x == 240) {
        // tokpos[s][d] = mean_t temb[tok[s,t]][d] + demb[s][d] + traitb[d] + intentb[d]
        float* tp = (float*)(dst + TOKPOS_OFF);
        for (int idx = threadIdx.x; idx < 24 * 64; idx += 256) {
            int s = idx >> 6, d = idx & 63;
            float a = 0.f;
#pragma unroll
            for (int t = 0; t < 8; ++t) a += temb[tok[s * 8 + t] * 64 + d];
            tp[idx] = a * 0.125f + demb[idx] + traitb[d] + intentb[d];
        }
        return;
    }
    int i = (blockIdx.x * 256 + threadIdx.x) * 4;
    const float* src;
    int off;
    float scl = 1.f;
    if (i < 36864)       { src = wqkv; off = 0;
                           if (((i >> 6) % 192) < 64) scl = QSCL; }   // q rows
    else if (i < 49152)  { src = wo;   off = 36864; }
    else if (i < 147456) { src = w1;   off = 49152; }
    else                 { src = w2;   off = 147456; }
    floatx4 v = *(const floatx4*)&src[i - off];
    f16x4 o;
    o[0] = (f16)(v[0] * scl); o[1] = (f16)(v[1] * scl);
    o[2] = (f16)(v[2] * scl); o[3] = (f16)(v[3] * scl);
    *(f16x4*)&dst[i] = o;
}

__device__ inline f16x4 pack4(float a, float b, float c, float d) {
    f16x2 lo = __builtin_bit_cast(f16x2, __builtin_amdgcn_cvt_pkrtz(a, b));
    f16x2 hi = __builtin_bit_cast(f16x2, __builtin_amdgcn_cvt_pkrtz(c, d));
    f16x4 r; r[0] = lo[0]; r[1] = lo[1]; r[2] = hi[0]; r[3] = hi[1];
    return r;
}

// f16 transcendentals (VOP1, gfx9+)
__device__ inline f16 exp2h(f16 x) { f16 r; asm("v_exp_f16 %0, %1" : "=v"(r) : "v"(x)); return r; }
__device__ inline f16 rcph(f16 x)  { f16 r; asm("v_rcp_f16 %0, %1" : "=v"(r) : "v"(x)); return r; }

// packed-f16 gelu: x * sigmoid(1.5958*(x+0.044715x^3)) in exp2 domain.
__device__ inline f16x2 gelu_pk(f16x2 x) {
    const f16 k044 = (f16)0.044715f;
    const f16 kone = (f16)1.f;
    const f16 km   = (f16)-2.302585f;   // 1.5957691 * log2(e) folded
    f16x2 c044 = {k044, k044};
    f16x2 one  = {kone, kone};
    f16x2 cm   = {km, km};
    f16x2 x2 = x * x;
    f16x2 u  = x2 * c044 + one;
    f16x2 arg = (x * u) * cm;
    f16x2 z;
    z[0] = exp2h(arg[0]);
    z[1] = exp2h(arg[1]);
    f16x2 d = z + one;
    f16x2 r;
    r[0] = rcph(d[0]);
    r[1] = rcph(d[1]);
    return x * r;
}

__global__ __launch_bounds__(256, 4) void fused_tfm_kernel(Params p) {
    // LDS: (5120 + 15360) f16 = 40960 B -> exactly 4 blocks/CU
    __shared__ __align__(16) f16 xlds[BUF];          // x (residual stream); pad rows 70-79 host linv
    __shared__ __align__(16) f16 scratch[3 * BUF];   // q|k|vT, then h; head reuses as float

    f16* qbuf = scratch;
    f16* kbuf = scratch + BUF;
    f16* vbuf = scratch + 2 * BUF;       // vT[2][64][40] during attn; LN wave-partials after
    f16* hbuf = scratch;                 // FF h-chunk: 80x128 swizzled, overlays dead q|k

    const int tid = threadIdx.x;
    const int lane = tid & 63;
    const int w = tid >> 6;
    const int l15 = lane & 15;
    const int quad = lane >> 4;
    const int b0 = blockIdx.x * G;

    // ---------- build x in LDS (f16, swizzled) ----------
    for (int idx = tid; idx < G * S * 64; idx += 256) {
        int i = idx / (S * 64);
        int rem = idx - i * S * 64;
        int r = rem >> 6, d = rem & 63;
        int b = b0 + i;
        float v;
        if (r == 0) {
            v = p.cls[d];
        } else if (r <= 24) {
            int s = r - 1;
            v = p.tokpos[s * 64 + d] + p.traits[b * 48 + s * 2] * p.traitW[d * 2]
                + p.traits[b * 48 + s * 2 + 1] * p.traitW[d * 2 + 1]
                + p.relg[b * 24 + s] * p.intentW[d];
        } else {
            v = p.mem[b * 640 + (r - 25) * 64 + d];
        }
        xlds[sw64(i * S + r, d)] = (f16)v;
    }
    for (int idx = tid; idx < (RP - G * S) * 64; idx += 256) {
        int r = G * S + (idx >> 6), d = idx & 63;
        xlds[sw64(r, d)] = (f16)0.f;
    }
    __syncthreads();

    // ---------- layers ----------
#pragma unroll 1
    for (int l = 0; l < NL; ++l) {
        const f16* Wqkv_l = p.Wqkv + l * 192 * 64;
        const float* bqkv_l = p.bqkv + l * 192;
        const f16* Wo_l = p.Wo + l * 64 * 64;
        const float* bo_l = p.bo + l * 64;
        const float* ln1g_l = p.ln1g + l * 64;
        const float* ln1b_l = p.ln1b + l * 64;
        const f16* W1_l = p.W1 + l * 512 * 64;
        const float* b1_l = p.b1 + l * 512;
        const f16* W2_l = p.W2 + l * 64 * 512;
        const float* b2_l = p.b2 + l * 64;
        const float* ln2g_l = p.ln2g + l * 64;
        const float* ln2b_l = p.ln2b + l * 64;

        // ===== QKV GEMM (swapped D^T). Wq pre-scaled by QSCL; v stored transposed =====
        {
            f16x8 xb[MT][2];
#pragma unroll
            for (int m = 0; m < MT; ++m)
#pragma unroll
                for (int kf = 0; kf < 2; ++kf)
                    xb[m][kf] = *(const f16x8*)&xlds[sw64(m * 16 + l15, kf * 32 + quad * 8)];
#pragma unroll
            for (int nt = w; nt < 12; nt += 4) {
                f16x8 wf0 = *(const f16x8*)&Wqkv_l[(nt * 16 + l15) * 64 + quad * 8];
                f16x8 wf1 = *(const f16x8*)&Wqkv_l[(nt * 16 + l15) * 64 + 32 + quad * 8];
                floatx4 bias4 = *(const floatx4*)&bqkv_l[nt * 16 + quad * 4];
                floatx4 acc[MT];
                PRIO1();
#pragma unroll
                for (int m = 0; m < MT; ++m) {
                    acc[m] = {0.f, 0.f, 0.f, 0.f};
                    acc[m] = MFMA(wf0, xb[m][0], acc[m]);
                    acc[m] = MFMA(wf1, xb[m][1], acc[m]);
                }
                PRIO0();
                if (nt < 4) {
                    int oc = nt * 16 + quad * 4;
                    floatx4 bq = bias4 * QSCL;   // bias scaled to match pre-scaled Wq
#pragma unroll
                    for (int m = 0; m < MT; ++m) {
                        int row = m * 16 + l15;
                        *(f16x4*)&qbuf[sw64(row, oc)] =
                            pack4(acc[m][0] + bq[0], acc[m][1] + bq[1],
                                  acc[m][2] + bq[2], acc[m][3] + bq[3]);
                    }
                } else if (nt < 8) {
                    int oc = (nt - 4) * 16 + quad * 4;
#pragma unroll
                    for (int m = 0; m < MT; ++m) {
                        int row = m * 16 + l15;
                        *(f16x4*)&kbuf[sw64(row, oc)] =
                            pack4(acc[m][0] + bias4[0], acc[m][1] + bias4[1],
                                  acc[m][2] + bias4[2], acc[m][3] + bias4[3]);
                    }
                } else {
                    // vT[item][d][j]: row stride 40, per-item stride 2560
                    int oc = (nt - 8) * 16 + quad * 4;
#pragma unroll
                    for (int m = 0; m < MT; ++m) {
                        int row = m * 16 + l15;
                        if (row < 70) {
                            int ii = row >= 35 ? 1 : 0;
                            f16* vp = vbuf + ii * 2560 + oc * 40 + (row - ii * 35);
                            vp[0]   = (f16)(acc[m][0] + bias4[0]);
                            vp[40]  = (f16)(acc[m][1] + bias4[1]);
                            vp[80]  = (f16)(acc[m][2] + bias4[2]);
                            vp[120] = (f16)(acc[m][3] + bias4[3]);
                        }
                    }
                }
            }
            // zero vT col 35 (read by the clamped jt=2 tail frag; must be finite)
            if (tid < 128) vbuf[(tid >> 6) * 2560 + (tid & 63) * 40 + 35] = (f16)0.f;
        }
        __syncthreads();

        // Wo weight/bias loads: global-only deps, latency hides under attention
        f16x8 wo_f0 = *(const f16x8*)&Wo_l[(w * 16 + l15) * 64 + quad * 8];
        f16x8 wo_f1 = *(const f16x8*)&Wo_l[(w * 16 + l15) * 64 + 32 + quad * 8];
        floatx4 bo4 = *(const floatx4*)&bo_l[w * 16 + quad * 4];

        // ===== attention via 16x16x16 MFMA: 16 (item,head) jobs, 4 per wave =====
        // scores C[j,q] = MFMA(K-frag, Q-frag); exp2'd C-frag doubles as PV B-frag.
        // Normalization DEFERRED: store unnormalized PV; 1/lsum -> linv (xlds pad rows),
        // applied in the Wo epilogue (row-scale commutes with x @ Wo^T).
        {
            f16x4 z4 = {};
            floatx4 zf = {0.f, 0.f, 0.f, 0.f};
            float* linv = (float*)&xlds[70 * 64];   // 80 floats in dead pad rows
#pragma unroll 2
            for (int jj = 0; jj < 4; ++jj) {
                int job = w * 4 + jj;
                int i = job >> 3;
                int h = job & 7;
                int rbase = i * S;
                int ccol = h * 8 + (quad & 1) * 4;
                f16x4 kf[3], vf[3], qf[3];
#pragma unroll
                for (int jt = 0; jt < 3; ++jt) {
                    f16x4 t = *(const f16x4*)&kbuf[sw64(rbase + jt * 16 + l15, ccol)];
                    kf[jt] = (quad >= 2) ? z4 : t;
                }
                const f16* vTb = vbuf + i * 2560 + (h * 8 + (l15 & 7)) * 40;
                vf[0] = *(const f16x4*)&vTb[quad * 4];
                vf[1] = *(const f16x4*)&vTb[16 + quad * 4];
                vf[2] = *(const f16x4*)&vTb[32];   // clamped: tail slots have P==0
#pragma unroll
                for (int qt = 0; qt < 3; ++qt)
                    qf[qt] = *(const f16x4*)&qbuf[sw64(rbase + qt * 16 + l15, ccol)];

#pragma unroll
                for (int qt = 0; qt < 3; ++qt) {
                    PRIO1();
                    floatx4 s0 = MFMA16(kf[0], qf[qt], zf);
                    floatx4 s1 = MFMA16(kf[1], qf[qt], zf);
                    floatx4 s2 = MFMA16(kf[2], qf[qt], zf);
                    PRIO0();
                    float e[12];
                    float lsum = 0.f;
#pragma unroll
                    for (int r = 0; r < 4; ++r) {
                        e[r] = __builtin_amdgcn_exp2f(s0[r]);
                        lsum += e[r];
                    }
#pragma unroll
                    for (int r = 0; r < 4; ++r) {
                        e[4 + r] = __builtin_amdgcn_exp2f(s1[r]);
                        lsum += e[4 + r];
                    }
#pragma unroll
                    for (int r = 0; r < 4; ++r) {
                        // j = 32 + quad*4 + r must be < 35
                        float v = __builtin_amdgcn_exp2f(s2[r]);
                        v = (quad == 0 && r < 3) ? v : 0.f;
                        e[8 + r] = v;
                        lsum += v;
                    }
                    f16x4 p0 = pack4(e[0], e[1], e[2], e[3]);
                    f16x4 p1 = pack4(e[4], e[5], e[6], e[7]);
                    f16x4 p2 = pack4(e[8], e[9], e[10], e[11]);
                    floatx4 acc = {0.f, 0.f, 0.f, 0.f};
                    PRIO1();
                    acc = MFMA16(vf[0], p0, acc);
                    acc = MFMA16(vf[1], p1, acc);
                    acc = MFMA16(vf[2], p2, acc);
                    PRIO0();
                    // store unnormalized PV immediately (short chain)
                    if (quad < 2 && (qt < 2 || l15 < 3)) {
                        *(f16x4*)&qbuf[sw64(rbase + qt * 16 + l15, h * 8 + quad * 4)] =
                            pack4(acc[0], acc[1], acc[2], acc[3]);
                    }
                    // lsum reduction runs in the shadow
                    lsum += __shfl_xor(lsum, 16, 64);
                    lsum += __shfl_xor(lsum, 32, 64);
                    if (quad == 0 && (qt < 2 || l15 < 3))
                        linv[rbase + qt * 16 + l15] = __builtin_amdgcn_rcpf(lsum);
                }
            }
        }
        __syncthreads();

        const int oc = w * 16 + quad * 4;

        // ===== Wo GEMM (swapped) + deferred 1/lsum + residual + FUSED LN1 =====
        // y stays in registers; per-row stats via quad-shfl + cross-wave LDS partials;
        // all 256 threads apply LN and write x. vbuf (dead vT) holds the partials.
        {
            const float* linv = (const float*)&xlds[70 * 64];
            float* wp = (float*)vbuf;   // [w][80] float2 (sum, sumsq)
            f16x8 ab[MT][2];
#pragma unroll
            for (int m = 0; m < MT; ++m)
#pragma unroll
                for (int kf = 0; kf < 2; ++kf)
                    ab[m][kf] = *(const f16x8*)&qbuf[sw64(m * 16 + l15, kf * 32 + quad * 8)];
            floatx4 oacc[MT];
            PRIO1();
#pragma unroll
            for (int m = 0; m < MT; ++m) {
                oacc[m] = {0.f, 0.f, 0.f, 0.f};
                oacc[m] = MFMA(wo_f0, ab[m][0], oacc[m]);
                oacc[m] = MFMA(wo_f1, ab[m][1], oacc[m]);
            }
            PRIO0();
#pragma unroll
            for (int m = 0; m < MT; ++m) {
                int row = m * 16 + l15;
                float iv = linv[row];
                f16x4 res = *(const f16x4*)&xlds[sw64(row, oc)];
                oacc[m][0] = oacc[m][0] * iv + bo4[0] + (float)res[0];
                oacc[m][1] = oacc[m][1] * iv + bo4[1] + (float)res[1];
                oacc[m][2] = oacc[m][2] * iv + bo4[2] + (float)res[2];
                oacc[m][3] = oacc[m][3] * iv + bo4[3] + (float)res[3];
                float ps = oacc[m][0] + oacc[m][1] + oacc[m][2] + oacc[m][3];
                float pq = oacc[m][0] * oacc[m][0] + oacc[m][1] * oacc[m][1]
                         + oacc[m][2] * oacc[m][2] + oacc[m][3] * oacc[m][3];
                ps += __shfl_xor(ps, 16, 64);
                pq += __shfl_xor(pq, 16, 64);
                ps += __shfl_xor(ps, 32, 64);
                pq += __shfl_xor(pq, 32, 64);
                if (quad == 0) {
                    floatx2 st = {ps, pq};
                    *(floatx2*)&wp[(w * 80 + row) * 2] = st;
                }
            }
            __syncthreads();
#pragma unroll
            for (int m = 0; m < MT; ++m) {
                int row = m * 16 + l15;
                floatx2 t0 = *(const floatx2*)&wp[(0 * 80 + row) * 2];
                floatx2 t1 = *(const floatx2*)&wp[(1 * 80 + row) * 2];
                floatx2 t2 = *(const floatx2*)&wp[(2 * 80 + row) * 2];
                floatx2 t3 = *(const floatx2*)&wp[(3 * 80 + row) * 2];
                float s = t0[0] + t1[0] + t2[0] + t3[0];
                float q = t0[1] + t1[1] + t2[1] + t3[1];
                float mean = s * (1.f / 64.f);
                float rs = rsqrtf(q * (1.f / 64.f) - mean * mean + 1e-5f);
                floatx4 g4 = *(const floatx4*)&ln1g_l[oc];
                floatx4 b4 = *(const floatx4*)&ln1b_l[oc];
                *(f16x4*)&xlds[sw64(row, oc)] =
                    pack4((oacc[m][0] - mean) * rs * g4[0] + b4[0],
                          (oacc[m][1] - mean) * rs * g4[1] + b4[1],
                          (oacc[m][2] - mean) * rs * g4[2] + b4[2],
                          (oacc[m][3] - mean) * rs * g4[3] + b4[3]);
            }
        }
        __syncthreads();

        // ===== FF: 4 chunks of 128 (swapped GEMMs), W2 accumulators persistent =====
        {
            f16x8 a2[MT][2];
#pragma unroll
            for (int m = 0; m < MT; ++m)
#pragma unroll
                for (int kf = 0; kf < 2; ++kf)
                    a2[m][kf] = *(const f16x8*)&xlds[sw64(m * 16 + l15, kf * 32 + quad * 8)];
            floatx4 facc[MT];
#pragma unroll
            for (int m = 0; m < MT; ++m) facc[m] = {0.f, 0.f, 0.f, 0.f};

#pragma unroll 1
            for (int c = 0; c < 4; ++c) {
#pragma unroll
                for (int ntl = w; ntl < 8; ntl += 4) {
                    int gc = c * 128 + ntl * 16;
                    f16x8 w1f0 = *(const f16x8*)&W1_l[(gc + l15) * 64 + quad * 8];
                    f16x8 w1f1 = *(const f16x8*)&W1_l[(gc + l15) * 64 + 32 + quad * 8];
                    floatx4 b14 = *(const floatx4*)&b1_l[gc + quad * 4];
                    int hc = ntl * 16 + quad * 4;
                    floatx4 hacc[MT];
                    PRIO1();
#pragma unroll
                    for (int m = 0; m < MT; ++m) {
                        hacc[m] = {0.f, 0.f, 0.f, 0.f};
                        hacc[m] = MFMA(w1f0, a2[m][0], hacc[m]);
                        hacc[m] = MFMA(w1f1, a2[m][1], hacc[m]);
                    }
                    PRIO0();
#pragma unroll
                    for (int m = 0; m < MT; ++m) {
                        int row = m * 16 + l15;
                        f16x2 lo = __builtin_bit_cast(f16x2,
                            __builtin_amdgcn_cvt_pkrtz(hacc[m][0] + b14[0], hacc[m][1] + b14[1]));
                        f16x2 hi = __builtin_bit_cast(f16x2,
                            __builtin_amdgcn_cvt_pkrtz(hacc[m][2] + b14[2], hacc[m][3] + b14[3]));
                        lo = gelu_pk(lo);
                        hi = gelu_pk(hi);
                        f16x4 hv;
                        hv[0] = lo[0]; hv[1] = lo[1]; hv[2] = hi[0]; hv[3] = hi[1];
                        *(f16x4*)&hbuf[sw128(row, hc)] = hv;
                    }
                }
                // W2 frag loads issued BEFORE the barrier: global-only deps
                f16x8 w2f[4];
#pragma unroll
                for (int kf = 0; kf < 4; ++kf)
                    w2f[kf] = *(const f16x8*)&W2_l[(w * 16 + l15) * 512 + c * 128 + kf * 32 + quad * 8];
                __syncthreads();
                PRIO1();
#pragma unroll
                for (int m = 0; m < MT; ++m) {
                    f16x8 h0 = *(const f16x8*)&hbuf[sw128(m * 16 + l15, 0 + quad * 8)];
                    f16x8 h1 = *(const f16x8*)&hbuf[sw128(m * 16 + l15, 32 + quad * 8)];
                    f16x8 h2 = *(const f16x8*)&hbuf[sw128(m * 16 + l15, 64 + quad * 8)];
                    f16x8 h3 = *(const f16x8*)&hbuf[sw128(m * 16 + l15, 96 + quad * 8)];
                    facc[m] = MFMA(w2f[0], h0, facc[m]);
                    facc[m] = MFMA(w2f[1], h1, facc[m]);
                    facc[m] = MFMA(w2f[2], h2, facc[m]);
                    facc[m] = MFMA(w2f[3], h3, facc[m]);
                }
                PRIO0();
                __syncthreads();
            }

            // ===== y2 = ff + b2 + x, FUSED LN2 (same partial scheme; vbuf free) =====
            float* wp = (float*)vbuf;
            floatx4 b24 = *(const floatx4*)&b2_l[oc];
#pragma unroll
            for (int m = 0; m < MT; ++m) {
                int row = m * 16 + l15;
                f16x4 res = *(const f16x4*)&xlds[sw64(row, oc)];
                facc[m][0] = facc[m][0] + b24[0] + (float)res[0];
                facc[m][1] = facc[m][1] + b24[1] + (float)res[1];
                facc[m][2] = facc[m][2] + b24[2] + (float)res[2];
                facc[m][3] = facc[m][3] + b24[3] + (float)res[3];
                float ps = facc[m][0] + facc[m][1] + facc[m][2] + facc[m][3];
                float pq = facc[m][0] * facc[m][0] + facc[m][1] * facc[m][1]
                         + facc[m][2] * facc[m][2] + facc[m][3] * facc[m][3];
                ps += __shfl_xor(ps, 16, 64);
                pq += __shfl_xor(pq, 16, 64);
                ps += __shfl_xor(ps, 32, 64);
                pq += __shfl_xor(pq, 32, 64);
                if (quad == 0) {
                    floatx2 st = {ps, pq};
                    *(floatx2*)&wp[(w * 80 + row) * 2] = st;
                }
            }
            __syncthreads();
#pragma unroll
            for (int m = 0; m < MT; ++m) {
                int row = m * 16 + l15;
                floatx2 t0 = *(const floatx2*)&wp[(0 * 80 + row) * 2];
                floatx2 t1 = *(const floatx2*)&wp[(1 * 80 + row) * 2];
                floatx2 t2 = *(const floatx2*)&wp[(2 * 80 + row) * 2];
                floatx2 t3 = *(const floatx2*)&wp[(3 * 80 + row) * 2];
                float s = t0[0] + t1[0] + t2[0] + t3[0];
                float q = t0[1] + t1[1] + t2[1] + t3[1];
                float mean = s * (1.f / 64.f);
                float rs = rsqrtf(q * (1.f / 64.f) - mean * mean + 1e-5f);
                floatx4 g4 = *(const floatx4*)&ln2g_l[oc];
                floatx4 b4 = *(const floatx4*)&ln2b_l[oc];
                *(f16x4*)&xlds[sw64(row, oc)] =
                    pack4((facc[m][0] - mean) * rs * g4[0] + b4[0],
                          (facc[m][1] - mean) * rs * g4[1] + b4[1],
                          (facc[m][2] - mean) * rs * g4[2] + b4[2],
                          (facc[m][3] - mean) * rs * g4[3] + b4[3]);
            }
        }
        __syncthreads();
    }

    // ---------- head: situation = ln(x[:,0] @ outW^T + outb) ----------
    float* sitlds = (float*)scratch;  // scratch dead after last LN2 (barrier above)
    {
        int i = tid >> 7, j = tid & 127;
        float s = p.outb[j];
#pragma unroll
        for (int kv = 0; kv < 8; ++kv) {
            f16x8 xv = *(const f16x8*)&xlds[sw64(i * S, kv * 8)];
            floatx4 w0 = *(const floatx4*)&p.outW[j * 64 + kv * 8];
            floatx4 w1 = *(const floatx4*)&p.outW[j * 64 + kv * 8 + 4];
#pragma unroll
            for (int e = 0; e < 4; ++e) s += (float)xv[e] * w0[e];
#pragma unroll
            for (int e = 0; e < 4; ++e) s += (float)xv[4 + e] * w1[e];
        }
        sitlds[i * 128 + j] = s;
    }
    __syncthreads();

    if (w < 2) {
        int i = w;
        float v0 = sitlds[i * 128 + lane];
        float v1 = sitlds[i * 128 + 64 + lane];
        float sum = v0 + v1, sq = v0 * v0 + v1 * v1;
#pragma unroll
        for (int off = 32; off >= 1; off >>= 1) {
            sum += __shfl_xor(sum, off, 64);
            sq += __shfl_xor(sq, off, 64);
        }
        float mean = sum * (1.f / 128.f);
        float rs = rsqrtf(sq * (1.f / 128.f) - mean * mean + 1e-5f);
        int b = b0 + i;
        p.out[b * 128 + lane] = (v0 - mean) * rs * p.olng[lane] + p.olnb[lane];
        p.out[b * 128 + 64 + lane] = (v1 - mean) * rs * p.olng[64 + lane] + p.olnb[64 + lane];
    }

    // situation_sequence: x rows 1..24 -> fp32
    for (int pp = tid; pp < G * 384; pp += 256) {
        int i = pp / 384;
        int q = pp - i * 384;
        int s = q >> 4, dp = (q & 15) * 4;
        int b = b0 + i;
        f16x4 xv = *(const f16x4*)&xlds[sw64(i * S + 1 + s, dp)];
        floatx4 o = {(float)xv[0], (float)xv[1], (float)xv[2], (float)xv[3]};
        *(floatx4*)&p.out[SEQOFF + b * 1536 + s * 64 + dp] = o;
    }
    // new_memory rows 0..8: passthrough of memory_context rows 1..9
    for (int pp = tid; pp < G * 144; pp += 256) {
        int i = pp / 144;
        int q = pp - i * 144;
        int mr = q >> 4, dp = (q & 15) * 4;
        int b = b0 + i;
        floatx4 v = *(const floatx4*)&p.mem[b * 640 + (1 + mr) * 64 + dp];
        *(floatx4*)&p.out[MEMOFF + b * 640 + mr * 64 + dp] = v;
    }
    // new_memory row 9: mean of x rows 1..24
    if (tid < G * 64) {
        int i = tid >> 6, d = tid & 63;
        float s = 0.f;
#pragma unroll
        for (int sr = 0; sr < 24; ++sr) s += (float)xlds[sw64(i * S + 1 + sr, d)];
        p.out[MEMOFF + (b0 + i) * 640 + 576 + d] = s * (1.f / 24.f);
    }
}

extern "C" void kernel_launch(void* const* d_in, const int* in_sizes, int n_in,
                              void* d_out, int out_size, void* d_ws, size_t ws_size,
                              hipStream_t stream) {
    (void)in_sizes; (void)n_in; (void)out_size; (void)ws_size;

    f16* ws = (f16*)d_ws;
    hipLaunchKernelGGL(cvt_all, dim3(241), dim3(256), 0, stream,
                       (const float*)d_in[11], (const float*)d_in[13],
                       (const float*)d_in[17], (const float*)d_in[19],
                       (const int*)d_in[0], (const float*)d_in[4],
                       (const float*)d_in[5], (const float*)d_in[7],
                       (const float*)d_in[9], ws);

    Params p;
    p.tok = (const int*)d_in[0];
    p.traits = (const float*)d_in[1];
    p.relg = (const float*)d_in[2];
    p.mem = (const float*)d_in[3];
    p.temb = (const float*)d_in[4];
    p.demb = (const float*)d_in[5];
    p.traitW = (const float*)d_in[6];
    p.traitb = (const float*)d_in[7];
    p.intentW = (const float*)d_in[8];
    p.intentb = (const float*)d_in[9];
    p.cls = (const float*)d_in[10];
    p.bqkv = (const float*)d_in[12];
    p.bo = (const float*)d_in[14];
    p.ln1g = (const float*)d_in[15];
    p.ln1b = (const float*)d_in[16];
    p.b1 = (const float*)d_in[18];
    p.b2 = (const float*)d_in[20];
    p.ln2g = (const float*)d_in[21];
    p.ln2b = (const float*)d_in[22];
    p.outW = (const float*)d_in[23];
    p.outb = (const float*)d_in[24];
    p.olng = (const float*)d_in[25];
    p.olnb = (const float*)d_in[26];
    p.Wqkv = ws;                 // 36864
    p.Wo = ws + 36864;           // 12288
    p.W1 = ws + 49152;           // 98304
    p.W2 = ws + 147456;          // 98304
    p.tokpos = (const float*)(ws + TOKPOS_OFF);
    p.out = (float*)d_out;

    hipLaunchKernelGGL(fused_tfm_kernel, dim3(4096 / G), dim3(256), 0, stream, p);
}

// Round 10
// 414.177 us; speedup vs baseline: 1.4100x; 1.0467x over previous
//
#include <hip/hip_runtime.h>

typedef _Float16 f16;
typedef _Float16 f16x2 __attribute__((ext_vector_type(2)));
typedef _Float16 f16x4 __attribute__((ext_vector_type(4)));
typedef _Float16 f16x8 __attribute__((ext_vector_type(8)));
typedef float floatx4 __attribute__((ext_vector_type(4)));

#define MFMA(a, b, c) __builtin_amdgcn_mfma_f32_16x16x32_f16((a), (b), (c), 0, 0, 0)
#define MFMA16(a, b, c) __builtin_amdgcn_mfma_f32_16x16x16f16((a), (b), (c), 0, 0, 0)

// Problem constants
constexpr int S = 35;        // 1 cls + 24 dims + 10 mem
constexpr int NH = 8;
constexpr int NL = 3;
constexpr int G = 2;         // batch items per block
constexpr int RP = 80;       // padded rows (G*35 = 70 -> 5 row-tiles)
constexpr int MT = 5;        // MFMA row-tiles
constexpr int BUF = RP * 64; // 5120 elems per swizzled 80x64 buffer
constexpr int SEQOFF = 4096 * 128;                 // 524288
constexpr int MEMOFF = SEQOFF + 4096 * 24 * 64;    // 6815744
constexpr int TOKPOS_OFF = 245760;                 // f16 elems into ws; tokpos floats live there
constexpr float QSCL = 0.51006982f;                // 1/sqrt(8) * log2(e), folded into q

// XOR swizzle: 8-col groups rotated by row&7 -> stride-64 rows, conflict-free patterns
__device__ __forceinline__ int sw64(int r, int c) {
    return (r << 6) + ((((c >> 3) ^ r) & 7) << 3) + (c & 7);
}
__device__ __forceinline__ int sw128(int r, int c) {
    return (r << 7) + ((((c >> 3) ^ (r & 7))) << 3) + (c & 7);
}

struct Params {
    const int* tok;
    const float *traits, *relg, *mem, *temb, *demb, *traitW, *traitb, *intentW, *intentb, *cls;
    const float *bqkv, *bo, *ln1g, *ln1b, *b1, *b2, *ln2g, *ln2b;
    const float *outW, *outb, *olng, *olnb;
    const f16 *Wqkv, *Wo, *W1, *W2;   // converted into d_ws
    const float* tokpos;              // precomputed in d_ws
    float* out;
};

// fp32->f16 weight conversion + tokpos precompute (block 240)
__global__ void cvt_all(const float* __restrict__ wqkv, const float* __restrict__ wo,
                        const float* __restrict__ w1, const float* __restrict__ w2,
                        const int* __restrict__ tok, const float* __restrict__ temb,
                        const float* __restrict__ demb, const float* __restrict__ traitb,
                        const float* __restrict__ intentb, f16* __restrict__ dst) {
    if (blockIdx.x == 240) {
        // tokpos[s][d] = mean_t temb[tok[s,t]][d] + demb[s][d] + traitb[d] + intentb[d]
        float* tp = (float*)(dst + TOKPOS_OFF);
        for (int idx = threadIdx.x; idx < 24 * 64; idx += 256) {
            int s = idx >> 6, d = idx & 63;
            float a = 0.f;
#pragma unroll
            for (int t = 0; t < 8; ++t) a += temb[tok[s * 8 + t] * 64 + d];
            tp[idx] = a * 0.125f + demb[idx] + traitb[d] + intentb[d];
        }
        return;
    }
    int i = (blockIdx.x * 256 + threadIdx.x) * 4;
    const float* src;
    int off;
    if (i < 36864)       { src = wqkv; off = 0; }
    else if (i < 49152)  { src = wo;   off = 36864; }
    else if (i < 147456) { src = w1;   off = 49152; }
    else                 { src = w2;   off = 147456; }
    floatx4 v = *(const floatx4*)&src[i - off];
    f16x4 o;
    o[0] = (f16)v[0]; o[1] = (f16)v[1]; o[2] = (f16)v[2]; o[3] = (f16)v[3];
    *(f16x4*)&dst[i] = o;
}

__device__ inline f16x4 pack4(float a, float b, float c, float d) {
    f16x2 lo = __builtin_bit_cast(f16x2, __builtin_amdgcn_cvt_pkrtz(a, b));
    f16x2 hi = __builtin_bit_cast(f16x2, __builtin_amdgcn_cvt_pkrtz(c, d));
    f16x4 r; r[0] = lo[0]; r[1] = lo[1]; r[2] = hi[0]; r[3] = hi[1];
    return r;
}

__device__ inline float gelu_f(float x) {
    // tanh-form gelu in exp2 domain: sigmoid(1.5958*(x+0.044715x^3)); max dev ~3e-4
    float x2 = x * x;
    float u = __builtin_fmaf(x2, 0.044715f, 1.0f);
    float xm = x * -2.302585f;           // 1.5957691 * log2(e) folded
    float z = __builtin_amdgcn_exp2f(xm * u);
    return x * __builtin_amdgcn_rcpf(1.f + z);
}

// LN with 2 threads per row: each handles 32 cols, combine sums via shfl_xor(1)
__device__ inline void ln_row_half(const f16* buf, f16* dst, int row, int half,
                                   const float* g, const float* bb) {
    float v[32];
    float sum = 0.f, sq = 0.f;
    int c0 = half * 32;
#pragma unroll
    for (int kv = 0; kv < 4; ++kv) {
        f16x8 x8 = *(const f16x8*)&buf[sw64(row, c0 + kv * 8)];
#pragma unroll
        for (int e = 0; e < 8; ++e) {
            float f = (float)x8[e];
            v[kv * 8 + e] = f;
            sum += f;
            sq += f * f;
        }
    }
    sum += __shfl_xor(sum, 1, 64);
    sq += __shfl_xor(sq, 1, 64);
    float mean = sum * (1.f / 64.f);
    float var = sq * (1.f / 64.f) - mean * mean;
    float rs = rsqrtf(var + 1e-5f);
#pragma unroll
    for (int kv = 0; kv < 8; ++kv) {
        floatx4 g4 = *(const floatx4*)&g[c0 + kv * 4];
        floatx4 b4 = *(const floatx4*)&bb[c0 + kv * 4];
        *(f16x4*)&dst[sw64(row, c0 + kv * 4)] =
            pack4((v[kv * 4 + 0] - mean) * rs * g4[0] + b4[0],
                  (v[kv * 4 + 1] - mean) * rs * g4[1] + b4[1],
                  (v[kv * 4 + 2] - mean) * rs * g4[2] + b4[2],
                  (v[kv * 4 + 3] - mean) * rs * g4[3] + b4[3]);
    }
}

__global__ __launch_bounds__(256, 4) void fused_tfm_kernel(Params p) {
    // LDS: (5120 + 15360) f16 = 40960 B -> exactly 4 blocks/CU
    __shared__ __align__(16) f16 xlds[BUF];          // x (residual stream)
    __shared__ __align__(16) f16 scratch[3 * BUF];   // q|k|vT, then h / y / y2; head reuses as float

    f16* qbuf = scratch;
    f16* kbuf = scratch + BUF;
    f16* vbuf = scratch + 2 * BUF;       // vT[2][64][40] during attn; y / y2 home after
    f16* hbuf = scratch;                 // FF h-chunk: 80x128 swizzled, overlays dead q|k

    const int tid = threadIdx.x;
    const int lane = tid & 63;
    const int w = tid >> 6;
    const int l15 = lane & 15;
    const int quad = lane >> 4;
    const int b0 = blockIdx.x * G;

    // ---------- build x in LDS (f16, swizzled) ----------
    for (int idx = tid; idx < G * S * 64; idx += 256) {
        int i = idx / (S * 64);
        int rem = idx - i * S * 64;
        int r = rem >> 6, d = rem & 63;
        int b = b0 + i;
        float v;
        if (r == 0) {
            v = p.cls[d];
        } else if (r <= 24) {
            int s = r - 1;
            v = p.tokpos[s * 64 + d] + p.traits[b * 48 + s * 2] * p.traitW[d * 2]
                + p.traits[b * 48 + s * 2 + 1] * p.traitW[d * 2 + 1]
                + p.relg[b * 24 + s] * p.intentW[d];
        } else {
            v = p.mem[b * 640 + (r - 25) * 64 + d];
        }
        xlds[sw64(i * S + r, d)] = (f16)v;
    }
    for (int idx = tid; idx < (RP - G * S) * 64; idx += 256) {
        int r = G * S + (idx >> 6), d = idx & 63;
        xlds[sw64(r, d)] = (f16)0.f;
    }
    __syncthreads();

    // ---------- layers ----------
#pragma unroll 1
    for (int l = 0; l < NL; ++l) {
        const f16* Wqkv_l = p.Wqkv + l * 192 * 64;
        const float* bqkv_l = p.bqkv + l * 192;
        const f16* Wo_l = p.Wo + l * 64 * 64;
        const float* bo_l = p.bo + l * 64;
        const float* ln1g_l = p.ln1g + l * 64;
        const float* ln1b_l = p.ln1b + l * 64;
        const f16* W1_l = p.W1 + l * 512 * 64;
        const float* b1_l = p.b1 + l * 512;
        const f16* W2_l = p.W2 + l * 64 * 512;
        const float* b2_l = p.b2 + l * 64;
        const float* ln2g_l = p.ln2g + l * 64;
        const float* ln2b_l = p.ln2b + l * 64;

        // ===== QKV GEMM (swapped D^T). q prescaled by QSCL; v stored transposed =====
        {
            f16x8 xb[MT][2];
#pragma unroll
            for (int m = 0; m < MT; ++m)
#pragma unroll
                for (int kf = 0; kf < 2; ++kf)
                    xb[m][kf] = *(const f16x8*)&xlds[sw64(m * 16 + l15, kf * 32 + quad * 8)];
#pragma unroll
            for (int nt = w; nt < 12; nt += 4) {
                f16x8 wf0 = *(const f16x8*)&Wqkv_l[(nt * 16 + l15) * 64 + quad * 8];
                f16x8 wf1 = *(const f16x8*)&Wqkv_l[(nt * 16 + l15) * 64 + 32 + quad * 8];
                floatx4 bias4 = *(const floatx4*)&bqkv_l[nt * 16 + quad * 4];
                floatx4 acc[MT];
#pragma unroll
                for (int m = 0; m < MT; ++m) {
                    acc[m] = {0.f, 0.f, 0.f, 0.f};
                    acc[m] = MFMA(wf0, xb[m][0], acc[m]);
                    acc[m] = MFMA(wf1, xb[m][1], acc[m]);
                }
                if (nt < 4) {
                    int oc = nt * 16 + quad * 4;
#pragma unroll
                    for (int m = 0; m < MT; ++m) {
                        int row = m * 16 + l15;
                        *(f16x4*)&qbuf[sw64(row, oc)] =
                            pack4((acc[m][0] + bias4[0]) * QSCL, (acc[m][1] + bias4[1]) * QSCL,
                                  (acc[m][2] + bias4[2]) * QSCL, (acc[m][3] + bias4[3]) * QSCL);
                    }
                } else if (nt < 8) {
                    int oc = (nt - 4) * 16 + quad * 4;
#pragma unroll
                    for (int m = 0; m < MT; ++m) {
                        int row = m * 16 + l15;
                        *(f16x4*)&kbuf[sw64(row, oc)] =
                            pack4(acc[m][0] + bias4[0], acc[m][1] + bias4[1],
                                  acc[m][2] + bias4[2], acc[m][3] + bias4[3]);
                    }
                } else {
                    // vT[item][d][j]: row stride 40, per-item stride 2560
                    int oc = (nt - 8) * 16 + quad * 4;
#pragma unroll
                    for (int m = 0; m < MT; ++m) {
                        int row = m * 16 + l15;
                        if (row < 70) {
                            int ii = row >= 35 ? 1 : 0;
                            f16* vp = vbuf + ii * 2560 + oc * 40 + (row - ii * 35);
                            vp[0]   = (f16)(acc[m][0] + bias4[0]);
                            vp[40]  = (f16)(acc[m][1] + bias4[1]);
                            vp[80]  = (f16)(acc[m][2] + bias4[2]);
                            vp[120] = (f16)(acc[m][3] + bias4[3]);
                        }
                    }
                }
            }
            // zero vT col 35 (read by the clamped jt=2 tail frag; must be finite)
            if (tid < 128) vbuf[(tid >> 6) * 2560 + (tid & 63) * 40 + 35] = (f16)0.f;
        }
        __syncthreads();

        // ===== attention via 16x16x16 MFMA: 16 (item,head) jobs, 4 per wave =====
        // scores C[j,q] = MFMA(K-frag, Q-frag) with d on k-slots 0..7 (8..15 zeroed);
        // exp2'd C-frag doubles as PV B-frag (identical lane layout); PV = MFMA(vT-frag, P).
        {
            f16x4 z4 = {};
            floatx4 zf = {0.f, 0.f, 0.f, 0.f};
#pragma unroll 1
            for (int jj = 0; jj < 4; ++jj) {
                int job = w * 4 + jj;
                int i = job >> 3;
                int h = job & 7;
                int rbase = i * S;
                int ccol = h * 8 + (quad & 1) * 4;
                f16x4 kf[3], vf[3], qf[3];
#pragma unroll
                for (int jt = 0; jt < 3; ++jt) {
                    f16x4 t = *(const f16x4*)&kbuf[sw64(rbase + jt * 16 + l15, ccol)];
                    kf[jt] = (quad >= 2) ? z4 : t;
                }
                const f16* vTb = vbuf + i * 2560 + (h * 8 + (l15 & 7)) * 40;
                vf[0] = *(const f16x4*)&vTb[quad * 4];
                vf[1] = *(const f16x4*)&vTb[16 + quad * 4];
                vf[2] = *(const f16x4*)&vTb[32];   // clamped: tail slots have P==0
#pragma unroll
                for (int qt = 0; qt < 3; ++qt)
                    qf[qt] = *(const f16x4*)&qbuf[sw64(rbase + qt * 16 + l15, ccol)];

#pragma unroll
                for (int qt = 0; qt < 3; ++qt) {
                    floatx4 s0 = MFMA16(kf[0], qf[qt], zf);
                    floatx4 s1 = MFMA16(kf[1], qf[qt], zf);
                    floatx4 s2 = MFMA16(kf[2], qf[qt], zf);
                    float e[12];
                    float lsum = 0.f;
#pragma unroll
                    for (int r = 0; r < 4; ++r) {
                        e[r] = __builtin_amdgcn_exp2f(s0[r]);
                        lsum += e[r];
                    }
#pragma unroll
                    for (int r = 0; r < 4; ++r) {
                        e[4 + r] = __builtin_amdgcn_exp2f(s1[r]);
                        lsum += e[4 + r];
                    }
#pragma unroll
                    for (int r = 0; r < 4; ++r) {
                        // j = 32 + quad*4 + r must be < 35
                        float v = __builtin_amdgcn_exp2f(s2[r]);
                        v = (quad == 0 && r < 3) ? v : 0.f;
                        e[8 + r] = v;
                        lsum += v;
                    }
                    f16x4 p0 = pack4(e[0], e[1], e[2], e[3]);
                    f16x4 p1 = pack4(e[4], e[5], e[6], e[7]);
                    f16x4 p2 = pack4(e[8], e[9], e[10], e[11]);
                    floatx4 acc = {0.f, 0.f, 0.f, 0.f};
                    acc = MFMA16(vf[0], p0, acc);
                    acc = MFMA16(vf[1], p1, acc);
                    acc = MFMA16(vf[2], p2, acc);
                    lsum += __shfl_xor(lsum, 16, 64);
                    lsum += __shfl_xor(lsum, 32, 64);
                    float inv = __builtin_amdgcn_rcpf(lsum);
                    if (quad < 2 && (qt < 2 || l15 < 3)) {
                        *(f16x4*)&qbuf[sw64(rbase + qt * 16 + l15, h * 8 + quad * 4)] =
                            pack4(acc[0] * inv, acc[1] * inv, acc[2] * inv, acc[3] * inv);
                    }
                }
            }
        }
        __syncthreads();

        // ===== Wo GEMM (swapped) + residual -> y in vbuf =====
        {
            f16x8 ab[MT][2];
#pragma unroll
            for (int m = 0; m < MT; ++m)
#pragma unroll
                for (int kf = 0; kf < 2; ++kf)
                    ab[m][kf] = *(const f16x8*)&qbuf[sw64(m * 16 + l15, kf * 32 + quad * 8)];
            f16x8 wf0 = *(const f16x8*)&Wo_l[(w * 16 + l15) * 64 + quad * 8];
            f16x8 wf1 = *(const f16x8*)&Wo_l[(w * 16 + l15) * 64 + 32 + quad * 8];
            int oc = w * 16 + quad * 4;
            floatx4 bo4 = *(const floatx4*)&bo_l[oc];
            floatx4 oacc[MT];
#pragma unroll
            for (int m = 0; m < MT; ++m) {
                oacc[m] = {0.f, 0.f, 0.f, 0.f};
                oacc[m] = MFMA(wf0, ab[m][0], oacc[m]);
                oacc[m] = MFMA(wf1, ab[m][1], oacc[m]);
            }
#pragma unroll
            for (int m = 0; m < MT; ++m) {
                int row = m * 16 + l15;
                f16x4 res = *(const f16x4*)&xlds[sw64(row, oc)];
                *(f16x4*)&vbuf[sw64(row, oc)] =
                    pack4(oacc[m][0] + bo4[0] + (float)res[0],
                          oacc[m][1] + bo4[1] + (float)res[1],
                          oacc[m][2] + bo4[2] + (float)res[2],
                          oacc[m][3] + bo4[3] + (float)res[3]);
            }
        }
        __syncthreads();

        // ===== LN1: y(vbuf) -> x =====
        if (tid < 2 * G * S) ln_row_half(vbuf, xlds, tid >> 1, tid & 1, ln1g_l, ln1b_l);
        __syncthreads();

        // ===== FF: 4 chunks of 128 (swapped GEMMs), W2 accumulators persistent =====
        {
            f16x8 a2[MT][2];
#pragma unroll
            for (int m = 0; m < MT; ++m)
#pragma unroll
                for (int kf = 0; kf < 2; ++kf)
                    a2[m][kf] = *(const f16x8*)&xlds[sw64(m * 16 + l15, kf * 32 + quad * 8)];
            floatx4 facc[MT];
#pragma unroll
            for (int m = 0; m < MT; ++m) facc[m] = {0.f, 0.f, 0.f, 0.f};

#pragma unroll 1
            for (int c = 0; c < 4; ++c) {
#pragma unroll
                for (int ntl = w; ntl < 8; ntl += 4) {
                    int gc = c * 128 + ntl * 16;
                    f16x8 w1f0 = *(const f16x8*)&W1_l[(gc + l15) * 64 + quad * 8];
                    f16x8 w1f1 = *(const f16x8*)&W1_l[(gc + l15) * 64 + 32 + quad * 8];
                    floatx4 b14 = *(const floatx4*)&b1_l[gc + quad * 4];
                    int oc = ntl * 16 + quad * 4;
                    floatx4 hacc[MT];
#pragma unroll
                    for (int m = 0; m < MT; ++m) {
                        hacc[m] = {0.f, 0.f, 0.f, 0.f};
                        hacc[m] = MFMA(w1f0, a2[m][0], hacc[m]);
                        hacc[m] = MFMA(w1f1, a2[m][1], hacc[m]);
                    }
#pragma unroll
                    for (int m = 0; m < MT; ++m) {
                        int row = m * 16 + l15;
                        *(f16x4*)&hbuf[sw128(row, oc)] =
                            pack4(gelu_f(hacc[m][0] + b14[0]), gelu_f(hacc[m][1] + b14[1]),
                                  gelu_f(hacc[m][2] + b14[2]), gelu_f(hacc[m][3] + b14[3]));
                    }
                }
                __syncthreads();
                f16x8 w2f[4];
#pragma unroll
                for (int kf = 0; kf < 4; ++kf)
                    w2f[kf] = *(const f16x8*)&W2_l[(w * 16 + l15) * 512 + c * 128 + kf * 32 + quad * 8];
#pragma unroll
                for (int m = 0; m < MT; ++m) {
                    f16x8 h0 = *(const f16x8*)&hbuf[sw128(m * 16 + l15, 0 + quad * 8)];
                    f16x8 h1 = *(const f16x8*)&hbuf[sw128(m * 16 + l15, 32 + quad * 8)];
                    f16x8 h2 = *(const f16x8*)&hbuf[sw128(m * 16 + l15, 64 + quad * 8)];
                    f16x8 h3 = *(const f16x8*)&hbuf[sw128(m * 16 + l15, 96 + quad * 8)];
                    facc[m] = MFMA(w2f[0], h0, facc[m]);
                    facc[m] = MFMA(w2f[1], h1, facc[m]);
                    facc[m] = MFMA(w2f[2], h2, facc[m]);
                    facc[m] = MFMA(w2f[3], h3, facc[m]);
                }
                __syncthreads();
            }

            // y2 = ff + b2 + x -> vbuf
            int oc = w * 16 + quad * 4;
            floatx4 b24 = *(const floatx4*)&b2_l[oc];
#pragma unroll
            for (int m = 0; m < MT; ++m) {
                int row = m * 16 + l15;
                f16x4 res = *(const f16x4*)&xlds[sw64(row, oc)];
                *(f16x4*)&vbuf[sw64(row, oc)] =
                    pack4(facc[m][0] + b24[0] + (float)res[0],
                          facc[m][1] + b24[1] + (float)res[1],
                          facc[m][2] + b24[2] + (float)res[2],
                          facc[m][3] + b24[3] + (float)res[3]);
            }
        }
        __syncthreads();

        // ===== LN2: y2(vbuf) -> x =====
        if (tid < 2 * G * S) ln_row_half(vbuf, xlds, tid >> 1, tid & 1, ln2g_l, ln2b_l);
        __syncthreads();
    }

    // ---------- head: situation = ln(x[:,0] @ outW^T + outb) ----------
    float* sitlds = (float*)scratch;  // scratch dead after last LN2 (barrier above)
    {
        int i = tid >> 7, j = tid & 127;
        float s = p.outb[j];
#pragma unroll
        for (int kv = 0; kv < 8; ++kv) {
            f16x8 xv = *(const f16x8*)&xlds[sw64(i * S, kv * 8)];
            floatx4 w0 = *(const floatx4*)&p.outW[j * 64 + kv * 8];
            floatx4 w1 = *(const floatx4*)&p.outW[j * 64 + kv * 8 + 4];
#pragma unroll
            for (int e = 0; e < 4; ++e) s += (float)xv[e] * w0[e];
#pragma unroll
            for (int e = 0; e < 4; ++e) s += (float)xv[4 + e] * w1[e];
        }
        sitlds[i * 128 + j] = s;
    }
    __syncthreads();

    if (w < 2) {
        int i = w;
        float v0 = sitlds[i * 128 + lane];
        float v1 = sitlds[i * 128 + 64 + lane];
        float sum = v0 + v1, sq = v0 * v0 + v1 * v1;
#pragma unroll
        for (int off = 32; off >= 1; off >>= 1) {
            sum += __shfl_xor(sum, off, 64);
            sq += __shfl_xor(sq, off, 64);
        }
        float mean = sum * (1.f / 128.f);
        float rs = rsqrtf(sq * (1.f / 128.f) - mean * mean + 1e-5f);
        int b = b0 + i;
        __builtin_nontemporal_store((v0 - mean) * rs * p.olng[lane] + p.olnb[lane],
                                    &p.out[b * 128 + lane]);
        __builtin_nontemporal_store((v1 - mean) * rs * p.olng[64 + lane] + p.olnb[64 + lane],
                                    &p.out[b * 128 + 64 + lane]);
    }

    // situation_sequence: x rows 1..24 -> fp32
    for (int pp = tid; pp < G * 384; pp += 256) {
        int i = pp / 384;
        int q = pp - i * 384;
        int s = q >> 4, dp = (q & 15) * 4;
        int b = b0 + i;
        f16x4 xv = *(const f16x4*)&xlds[sw64(i * S + 1 + s, dp)];
        floatx4 o = {(float)xv[0], (float)xv[1], (float)xv[2], (float)xv[3]};
        __builtin_nontemporal_store(o, (floatx4*)&p.out[SEQOFF + b * 1536 + s * 64 + dp]);
    }
    // new_memory rows 0..8: passthrough of memory_context rows 1..9
    for (int pp = tid; pp < G * 144; pp += 256) {
        int i = pp / 144;
        int q = pp - i * 144;
        int mr = q >> 4, dp = (q & 15) * 4;
        int b = b0 + i;
        floatx4 v = *(const floatx4*)&p.mem[b * 640 + (1 + mr) * 64 + dp];
        __builtin_nontemporal_store(v, (floatx4*)&p.out[MEMOFF + b * 640 + mr * 64 + dp]);
    }
    // new_memory row 9: mean of x rows 1..24
    if (tid < G * 64) {
        int i = tid >> 6, d = tid & 63;
        float s = 0.f;
#pragma unroll
        for (int sr = 0; sr < 24; ++sr) s += (float)xlds[sw64(i * S + 1 + sr, d)];
        __builtin_nontemporal_store(s * (1.f / 24.f), &p.out[MEMOFF + (b0 + i) * 640 + 576 + d]);
    }
}

extern "C" void kernel_launch(void* const* d_in, const int* in_sizes, int n_in,
                              void* d_out, int out_size, void* d_ws, size_t ws_size,
                              hipStream_t stream) {
    (void)in_sizes; (void)n_in; (void)out_size; (void)ws_size;

    f16* ws = (f16*)d_ws;
    hipLaunchKernelGGL(cvt_all, dim3(241), dim3(256), 0, stream,
                       (const float*)d_in[11], (const float*)d_in[13],
                       (const float*)d_in[17], (const float*)d_in[19],
                       (const int*)d_in[0], (const float*)d_in[4],
                       (const float*)d_in[5], (const float*)d_in[7],
                       (const float*)d_in[9], ws);

    Params p;
    p.tok = (const int*)d_in[0];
    p.traits = (const float*)d_in[1];
    p.relg = (const float*)d_in[2];
    p.mem = (const float*)d_in[3];
    p.temb = (const float*)d_in[4];
    p.demb = (const float*)d_in[5];
    p.traitW = (const float*)d_in[6];
    p.traitb = (const float*)d_in[7];
    p.intentW = (const float*)d_in[8];
    p.intentb = (const float*)d_in[9];
    p.cls = (const float*)d_in[10];
    p.bqkv = (const float*)d_in[12];
    p.bo = (const float*)d_in[14];
    p.ln1g = (const float*)d_in[15];
    p.ln1b = (const float*)d_in[16];
    p.b1 = (const float*)d_in[18];
    p.b2 = (const float*)d_in[20];
    p.ln2g = (const float*)d_in[21];
    p.ln2b = (const float*)d_in[22];
    p.outW = (const float*)d_in[23];
    p.outb = (const float*)d_in[24];
    p.olng = (const float*)d_in[25];
    p.olnb = (const float*)d_in[26];
    p.Wqkv = ws;                 // 36864
    p.Wo = ws + 36864;           // 12288
    p.W1 = ws + 49152;           // 98304
    p.W2 = ws + 147456;          // 98304
    p.tokpos = (const float*)(ws + TOKPOS_OFF);
    p.out = (float*)d_out;

    hipLaunchKernelGGL(fused_tfm_kernel, dim3(4096 / G), dim3(256), 0, stream, p);
}

// Round 11
// 400.842 us; speedup vs baseline: 1.4569x; 1.0333x over previous
//
#include <hip/hip_runtime.h>

typedef _Float16 f16;
typedef _Float16 f16x2 __attribute__((ext_vector_type(2)));
typedef _Float16 f16x4 __attribute__((ext_vector_type(4)));
typedef _Float16 f16x8 __attribute__((ext_vector_type(8)));
typedef float floatx4 __attribute__((ext_vector_type(4)));

#define MFMA(a, b, c) __builtin_amdgcn_mfma_f32_16x16x32_f16((a), (b), (c), 0, 0, 0)
#define MFMA16(a, b, c) __builtin_amdgcn_mfma_f32_16x16x16f16((a), (b), (c), 0, 0, 0)

// Problem constants
constexpr int S = 35;        // 1 cls + 24 dims + 10 mem
constexpr int NH = 8;
constexpr int NL = 3;
constexpr int G = 2;         // batch items per block
constexpr int RP = 80;       // padded rows (G*35 = 70 -> 5 row-tiles)
constexpr int MT = 5;        // MFMA row-tiles
constexpr int BUF = RP * 64; // 5120 elems per swizzled 80x64 buffer
constexpr int SEQOFF = 4096 * 128;                 // 524288
constexpr int MEMOFF = SEQOFF + 4096 * 24 * 64;    // 6815744
constexpr int TOKPOS_OFF = 245760;                 // f16 elems into ws; tokpos floats live there
constexpr float QSCL = 0.51006982f;                // 1/sqrt(8) * log2(e), folded into q

// XOR swizzle: 8-col groups rotated by row&7 -> stride-64 rows, conflict-free patterns
__device__ __forceinline__ int sw64(int r, int c) {
    return (r << 6) + ((((c >> 3) ^ r) & 7) << 3) + (c & 7);
}
__device__ __forceinline__ int sw128(int r, int c) {
    return (r << 7) + ((((c >> 3) ^ (r & 7))) << 3) + (c & 7);
}

struct Params {
    const int* tok;
    const float *traits, *relg, *mem, *temb, *demb, *traitW, *traitb, *intentW, *intentb, *cls;
    const float *bqkv, *bo, *ln1g, *ln1b, *b1, *b2, *ln2g, *ln2b;
    const float *outW, *outb, *olng, *olnb;
    const f16 *Wqkv, *Wo, *W1, *W2;   // converted into d_ws
    const float* tokpos;              // precomputed in d_ws
    float* out;
};

// fp32->f16 weight conversion + tokpos precompute (block 240)
__global__ void cvt_all(const float* __restrict__ wqkv, const float* __restrict__ wo,
                        const float* __restrict__ w1, const float* __restrict__ w2,
                        const int* __restrict__ tok, const float* __restrict__ temb,
                        const float* __restrict__ demb, const float* __restrict__ traitb,
                        const float* __restrict__ intentb, f16* __restrict__ dst) {
    if (blockIdx.x == 240) {
        // tokpos[s][d] = mean_t temb[tok[s,t]][d] + demb[s][d] + traitb[d] + intentb[d]
        float* tp = (float*)(dst + TOKPOS_OFF);
        for (int idx = threadIdx.x; idx < 24 * 64; idx += 256) {
            int s = idx >> 6, d = idx & 63;
            float a = 0.f;
#pragma unroll
            for (int t = 0; t < 8; ++t) a += temb[tok[s * 8 + t] * 64 + d];
            tp[idx] = a * 0.125f + demb[idx] + traitb[d] + intentb[d];
        }
        return;
    }
    int i = (blockIdx.x * 256 + threadIdx.x) * 4;
    const float* src;
    int off;
    if (i < 36864)       { src = wqkv; off = 0; }
    else if (i < 49152)  { src = wo;   off = 36864; }
    else if (i < 147456) { src = w1;   off = 49152; }
    else                 { src = w2;   off = 147456; }
    floatx4 v = *(const floatx4*)&src[i - off];
    f16x4 o;
    o[0] = (f16)v[0]; o[1] = (f16)v[1]; o[2] = (f16)v[2]; o[3] = (f16)v[3];
    *(f16x4*)&dst[i] = o;
}

__device__ inline f16x4 pack4(float a, float b, float c, float d) {
    f16x2 lo = __builtin_bit_cast(f16x2, __builtin_amdgcn_cvt_pkrtz(a, b));
    f16x2 hi = __builtin_bit_cast(f16x2, __builtin_amdgcn_cvt_pkrtz(c, d));
    f16x4 r; r[0] = lo[0]; r[1] = lo[1]; r[2] = hi[0]; r[3] = hi[1];
    return r;
}

__device__ inline float gelu_f(float x) {
    // tanh-form gelu in exp2 domain: sigmoid(1.5958*(x+0.044715x^3)); max dev ~3e-4
    float x2 = x * x;
    float u = __builtin_fmaf(x2, 0.044715f, 1.0f);
    float xm = x * -2.302585f;           // 1.5957691 * log2(e) folded
    float z = __builtin_amdgcn_exp2f(xm * u);
    return x * __builtin_amdgcn_rcpf(1.f + z);
}

// LN with 2 threads per row: each handles 32 cols, combine sums via shfl_xor(1)
__device__ inline void ln_row_half(const f16* buf, f16* dst, int row, int half,
                                   const float* g, const float* bb) {
    float v[32];
    float sum = 0.f, sq = 0.f;
    int c0 = half * 32;
#pragma unroll
    for (int kv = 0; kv < 4; ++kv) {
        f16x8 x8 = *(const f16x8*)&buf[sw64(row, c0 + kv * 8)];
#pragma unroll
        for (int e = 0; e < 8; ++e) {
            float f = (float)x8[e];
            v[kv * 8 + e] = f;
            sum += f;
            sq += f * f;
        }
    }
    sum += __shfl_xor(sum, 1, 64);
    sq += __shfl_xor(sq, 1, 64);
    float mean = sum * (1.f / 64.f);
    float var = sq * (1.f / 64.f) - mean * mean;
    float rs = rsqrtf(var + 1e-5f);
#pragma unroll
    for (int kv = 0; kv < 8; ++kv) {
        floatx4 g4 = *(const floatx4*)&g[c0 + kv * 4];
        floatx4 b4 = *(const floatx4*)&bb[c0 + kv * 4];
        *(f16x4*)&dst[sw64(row, c0 + kv * 4)] =
            pack4((v[kv * 4 + 0] - mean) * rs * g4[0] + b4[0],
                  (v[kv * 4 + 1] - mean) * rs * g4[1] + b4[1],
                  (v[kv * 4 + 2] - mean) * rs * g4[2] + b4[2],
                  (v[kv * 4 + 3] - mean) * rs * g4[3] + b4[3]);
    }
}

__global__ __launch_bounds__(256, 4) void fused_tfm_kernel(Params p) {
    // LDS: (5120 + 15360) f16 = 40960 B -> exactly 4 blocks/CU
    __shared__ __align__(16) f16 xlds[BUF];          // x (residual stream)
    __shared__ __align__(16) f16 scratch[3 * BUF];   // q|k|vT, then h / y / y2; head reuses as float

    f16* qbuf = scratch;
    f16* kbuf = scratch + BUF;
    f16* vbuf = scratch + 2 * BUF;       // vT[2][64][40] during attn; y / y2 home after
    f16* hbuf = scratch;                 // FF h-chunk: 80x128 swizzled, overlays dead q|k

    const int tid = threadIdx.x;
    const int lane = tid & 63;
    const int w = tid >> 6;
    const int l15 = lane & 15;
    const int quad = lane >> 4;
    const int b0 = blockIdx.x * G;

    // ---------- build x in LDS (f16, swizzled) ----------
    for (int idx = tid; idx < G * S * 64; idx += 256) {
        int i = idx / (S * 64);
        int rem = idx - i * S * 64;
        int r = rem >> 6, d = rem & 63;
        int b = b0 + i;
        float v;
        if (r == 0) {
            v = p.cls[d];
        } else if (r <= 24) {
            int s = r - 1;
            v = p.tokpos[s * 64 + d] + p.traits[b * 48 + s * 2] * p.traitW[d * 2]
                + p.traits[b * 48 + s * 2 + 1] * p.traitW[d * 2 + 1]
                + p.relg[b * 24 + s] * p.intentW[d];
        } else {
            v = p.mem[b * 640 + (r - 25) * 64 + d];
        }
        xlds[sw64(i * S + r, d)] = (f16)v;
    }
    for (int idx = tid; idx < (RP - G * S) * 64; idx += 256) {
        int r = G * S + (idx >> 6), d = idx & 63;
        xlds[sw64(r, d)] = (f16)0.f;
    }
    __syncthreads();

    // ---------- layers ----------
#pragma unroll 1
    for (int l = 0; l < NL; ++l) {
        const f16* Wqkv_l = p.Wqkv + l * 192 * 64;
        const float* bqkv_l = p.bqkv + l * 192;
        const f16* Wo_l = p.Wo + l * 64 * 64;
        const float* bo_l = p.bo + l * 64;
        const float* ln1g_l = p.ln1g + l * 64;
        const float* ln1b_l = p.ln1b + l * 64;
        const f16* W1_l = p.W1 + l * 512 * 64;
        const float* b1_l = p.b1 + l * 512;
        const f16* W2_l = p.W2 + l * 64 * 512;
        const float* b2_l = p.b2 + l * 64;
        const float* ln2g_l = p.ln2g + l * 64;
        const float* ln2b_l = p.ln2b + l * 64;

        // ===== QKV GEMM (swapped D^T). q prescaled by QSCL; v stored transposed =====
        // Wave w computes nt = w, w+4, w+8 -> q/k cols [16w,16w+16), vT rows [16w,16w+16):
        // exactly the fragments heads 2w, 2w+1 consume. Attention below is wave-local,
        // so NO barrier is needed between QKV and attention (compiler lgkmcnt orders
        // same-wave LDS ops).
        {
            f16x8 xb[MT][2];
#pragma unroll
            for (int m = 0; m < MT; ++m)
#pragma unroll
                for (int kf = 0; kf < 2; ++kf)
                    xb[m][kf] = *(const f16x8*)&xlds[sw64(m * 16 + l15, kf * 32 + quad * 8)];
#pragma unroll
            for (int nt = w; nt < 12; nt += 4) {
                f16x8 wf0 = *(const f16x8*)&Wqkv_l[(nt * 16 + l15) * 64 + quad * 8];
                f16x8 wf1 = *(const f16x8*)&Wqkv_l[(nt * 16 + l15) * 64 + 32 + quad * 8];
                floatx4 bias4 = *(const floatx4*)&bqkv_l[nt * 16 + quad * 4];
                floatx4 acc[MT];
#pragma unroll
                for (int m = 0; m < MT; ++m) {
                    acc[m] = {0.f, 0.f, 0.f, 0.f};
                    acc[m] = MFMA(wf0, xb[m][0], acc[m]);
                    acc[m] = MFMA(wf1, xb[m][1], acc[m]);
                }
                if (nt < 4) {
                    int oc = nt * 16 + quad * 4;
#pragma unroll
                    for (int m = 0; m < MT; ++m) {
                        int row = m * 16 + l15;
                        *(f16x4*)&qbuf[sw64(row, oc)] =
                            pack4((acc[m][0] + bias4[0]) * QSCL, (acc[m][1] + bias4[1]) * QSCL,
                                  (acc[m][2] + bias4[2]) * QSCL, (acc[m][3] + bias4[3]) * QSCL);
                    }
                } else if (nt < 8) {
                    int oc = (nt - 4) * 16 + quad * 4;
#pragma unroll
                    for (int m = 0; m < MT; ++m) {
                        int row = m * 16 + l15;
                        *(f16x4*)&kbuf[sw64(row, oc)] =
                            pack4(acc[m][0] + bias4[0], acc[m][1] + bias4[1],
                                  acc[m][2] + bias4[2], acc[m][3] + bias4[3]);
                    }
                } else {
                    // vT[item][d][j]: row stride 40, per-item stride 2560
                    int oc = (nt - 8) * 16 + quad * 4;
#pragma unroll
                    for (int m = 0; m < MT; ++m) {
                        int row = m * 16 + l15;
                        if (row < 70) {
                            int ii = row >= 35 ? 1 : 0;
                            f16* vp = vbuf + ii * 2560 + oc * 40 + (row - ii * 35);
                            vp[0]   = (f16)(acc[m][0] + bias4[0]);
                            vp[40]  = (f16)(acc[m][1] + bias4[1]);
                            vp[80]  = (f16)(acc[m][2] + bias4[2]);
                            vp[120] = (f16)(acc[m][3] + bias4[3]);
                        }
                    }
                }
            }
            // zero vT col 35 — per-wave: rows [16w,16w+16) for both items (the rows
            // this wave's attention jobs read)
            if (lane < 32) {
                int ii = lane >> 4;
                int d = w * 16 + (lane & 15);
                vbuf[ii * 2560 + d * 40 + 35] = (f16)0.f;
            }
        }
        // NO __syncthreads() here: attention jobs below are wave-local by construction.

        // ===== attention via 16x16x16 MFMA: wave w handles heads 2w,2w+1 x items 0,1 =====
        // scores C[j,q] = MFMA(K-frag, Q-frag) with d on k-slots 0..7 (8..15 zeroed);
        // exp2'd C-frag doubles as PV B-frag (identical lane layout); PV = MFMA(vT-frag, P).
        {
            f16x4 z4 = {};
            floatx4 zf = {0.f, 0.f, 0.f, 0.f};
#pragma unroll 1
            for (int jj = 0; jj < 4; ++jj) {
                int h = w * 2 + (jj & 1);
                int i = jj >> 1;
                int rbase = i * S;
                int ccol = h * 8 + (quad & 1) * 4;
                f16x4 kf[3], vf[3], qf[3];
#pragma unroll
                for (int jt = 0; jt < 3; ++jt) {
                    f16x4 t = *(const f16x4*)&kbuf[sw64(rbase + jt * 16 + l15, ccol)];
                    kf[jt] = (quad >= 2) ? z4 : t;
                }
                const f16* vTb = vbuf + i * 2560 + (h * 8 + (l15 & 7)) * 40;
                vf[0] = *(const f16x4*)&vTb[quad * 4];
                vf[1] = *(const f16x4*)&vTb[16 + quad * 4];
                vf[2] = *(const f16x4*)&vTb[32];   // clamped: tail slots have P==0
#pragma unroll
                for (int qt = 0; qt < 3; ++qt)
                    qf[qt] = *(const f16x4*)&qbuf[sw64(rbase + qt * 16 + l15, ccol)];

#pragma unroll
                for (int qt = 0; qt < 3; ++qt) {
                    floatx4 s0 = MFMA16(kf[0], qf[qt], zf);
                    floatx4 s1 = MFMA16(kf[1], qf[qt], zf);
                    floatx4 s2 = MFMA16(kf[2], qf[qt], zf);
                    float e[12];
                    float lsum = 0.f;
#pragma unroll
                    for (int r = 0; r < 4; ++r) {
                        e[r] = __builtin_amdgcn_exp2f(s0[r]);
                        lsum += e[r];
                    }
#pragma unroll
                    for (int r = 0; r < 4; ++r) {
                        e[4 + r] = __builtin_amdgcn_exp2f(s1[r]);
                        lsum += e[4 + r];
                    }
#pragma unroll
                    for (int r = 0; r < 4; ++r) {
                        // j = 32 + quad*4 + r must be < 35
                        float v = __builtin_amdgcn_exp2f(s2[r]);
                        v = (quad == 0 && r < 3) ? v : 0.f;
                        e[8 + r] = v;
                        lsum += v;
                    }
                    f16x4 p0 = pack4(e[0], e[1], e[2], e[3]);
                    f16x4 p1 = pack4(e[4], e[5], e[6], e[7]);
                    f16x4 p2 = pack4(e[8], e[9], e[10], e[11]);
                    floatx4 acc = {0.f, 0.f, 0.f, 0.f};
                    acc = MFMA16(vf[0], p0, acc);
                    acc = MFMA16(vf[1], p1, acc);
                    acc = MFMA16(vf[2], p2, acc);
                    lsum += __shfl_xor(lsum, 16, 64);
                    lsum += __shfl_xor(lsum, 32, 64);
                    float inv = __builtin_amdgcn_rcpf(lsum);
                    if (quad < 2 && (qt < 2 || l15 < 3)) {
                        *(f16x4*)&qbuf[sw64(rbase + qt * 16 + l15, h * 8 + quad * 4)] =
                            pack4(acc[0] * inv, acc[1] * inv, acc[2] * inv, acc[3] * inv);
                    }
                }
            }
        }
        __syncthreads();

        // ===== Wo GEMM (swapped) + residual -> y in vbuf =====
        {
            f16x8 ab[MT][2];
#pragma unroll
            for (int m = 0; m < MT; ++m)
#pragma unroll
                for (int kf = 0; kf < 2; ++kf)
                    ab[m][kf] = *(const f16x8*)&qbuf[sw64(m * 16 + l15, kf * 32 + quad * 8)];
            f16x8 wf0 = *(const f16x8*)&Wo_l[(w * 16 + l15) * 64 + quad * 8];
            f16x8 wf1 = *(const f16x8*)&Wo_l[(w * 16 + l15) * 64 + 32 + quad * 8];
            int oc = w * 16 + quad * 4;
            floatx4 bo4 = *(const floatx4*)&bo_l[oc];
            floatx4 oacc[MT];
#pragma unroll
            for (int m = 0; m < MT; ++m) {
                oacc[m] = {0.f, 0.f, 0.f, 0.f};
                oacc[m] = MFMA(wf0, ab[m][0], oacc[m]);
                oacc[m] = MFMA(wf1, ab[m][1], oacc[m]);
            }
#pragma unroll
            for (int m = 0; m < MT; ++m) {
                int row = m * 16 + l15;
                f16x4 res = *(const f16x4*)&xlds[sw64(row, oc)];
                *(f16x4*)&vbuf[sw64(row, oc)] =
                    pack4(oacc[m][0] + bo4[0] + (float)res[0],
                          oacc[m][1] + bo4[1] + (float)res[1],
                          oacc[m][2] + bo4[2] + (float)res[2],
                          oacc[m][3] + bo4[3] + (float)res[3]);
            }
        }
        __syncthreads();

        // ===== LN1: y(vbuf) -> x =====
        if (tid < 2 * G * S) ln_row_half(vbuf, xlds, tid >> 1, tid & 1, ln1g_l, ln1b_l);
        __syncthreads();

        // ===== FF: 4 chunks of 128 (swapped GEMMs), W2 accumulators persistent =====
        {
            f16x8 a2[MT][2];
#pragma unroll
            for (int m = 0; m < MT; ++m)
#pragma unroll
                for (int kf = 0; kf < 2; ++kf)
                    a2[m][kf] = *(const f16x8*)&xlds[sw64(m * 16 + l15, kf * 32 + quad * 8)];
            floatx4 facc[MT];
#pragma unroll
            for (int m = 0; m < MT; ++m) facc[m] = {0.f, 0.f, 0.f, 0.f};

#pragma unroll 1
            for (int c = 0; c < 4; ++c) {
#pragma unroll
                for (int ntl = w; ntl < 8; ntl += 4) {
                    int gc = c * 128 + ntl * 16;
                    f16x8 w1f0 = *(const f16x8*)&W1_l[(gc + l15) * 64 + quad * 8];
                    f16x8 w1f1 = *(const f16x8*)&W1_l[(gc + l15) * 64 + 32 + quad * 8];
                    floatx4 b14 = *(const floatx4*)&b1_l[gc + quad * 4];
                    int oc = ntl * 16 + quad * 4;
                    floatx4 hacc[MT];
#pragma unroll
                    for (int m = 0; m < MT; ++m) {
                        hacc[m] = {0.f, 0.f, 0.f, 0.f};
                        hacc[m] = MFMA(w1f0, a2[m][0], hacc[m]);
                        hacc[m] = MFMA(w1f1, a2[m][1], hacc[m]);
                    }
#pragma unroll
                    for (int m = 0; m < MT; ++m) {
                        int row = m * 16 + l15;
                        *(f16x4*)&hbuf[sw128(row, oc)] =
                            pack4(gelu_f(hacc[m][0] + b14[0]), gelu_f(hacc[m][1] + b14[1]),
                                  gelu_f(hacc[m][2] + b14[2]), gelu_f(hacc[m][3] + b14[3]));
                    }
                }
                __syncthreads();
                f16x8 w2f[4];
#pragma unroll
                for (int kf = 0; kf < 4; ++kf)
                    w2f[kf] = *(const f16x8*)&W2_l[(w * 16 + l15) * 512 + c * 128 + kf * 32 + quad * 8];
#pragma unroll
                for (int m = 0; m < MT; ++m) {
                    f16x8 h0 = *(const f16x8*)&hbuf[sw128(m * 16 + l15, 0 + quad * 8)];
                    f16x8 h1 = *(const f16x8*)&hbuf[sw128(m * 16 + l15, 32 + quad * 8)];
                    f16x8 h2 = *(const f16x8*)&hbuf[sw128(m * 16 + l15, 64 + quad * 8)];
                    f16x8 h3 = *(const f16x8*)&hbuf[sw128(m * 16 + l15, 96 + quad * 8)];
                    facc[m] = MFMA(w2f[0], h0, facc[m]);
                    facc[m] = MFMA(w2f[1], h1, facc[m]);
                    facc[m] = MFMA(w2f[2], h2, facc[m]);
                    facc[m] = MFMA(w2f[3], h3, facc[m]);
                }
                __syncthreads();
            }

            // y2 = ff + b2 + x -> vbuf
            int oc = w * 16 + quad * 4;
            floatx4 b24 = *(const floatx4*)&b2_l[oc];
#pragma unroll
            for (int m = 0; m < MT; ++m) {
                int row = m * 16 + l15;
                f16x4 res = *(const f16x4*)&xlds[sw64(row, oc)];
                *(f16x4*)&vbuf[sw64(row, oc)] =
                    pack4(facc[m][0] + b24[0] + (float)res[0],
                          facc[m][1] + b24[1] + (float)res[1],
                          facc[m][2] + b24[2] + (float)res[2],
                          facc[m][3] + b24[3] + (float)res[3]);
            }
        }
        __syncthreads();

        // ===== LN2: y2(vbuf) -> x =====
        if (tid < 2 * G * S) ln_row_half(vbuf, xlds, tid >> 1, tid & 1, ln2g_l, ln2b_l);
        __syncthreads();
    }

    // ---------- head: situation = ln(x[:,0] @ outW^T + outb) ----------
    float* sitlds = (float*)scratch;  // scratch dead after last LN2 (barrier above)
    {
        int i = tid >> 7, j = tid & 127;
        float s = p.outb[j];
#pragma unroll
        for (int kv = 0; kv < 8; ++kv) {
            f16x8 xv = *(const f16x8*)&xlds[sw64(i * S, kv * 8)];
            floatx4 w0 = *(const floatx4*)&p.outW[j * 64 + kv * 8];
            floatx4 w1 = *(const floatx4*)&p.outW[j * 64 + kv * 8 + 4];
#pragma unroll
            for (int e = 0; e < 4; ++e) s += (float)xv[e] * w0[e];
#pragma unroll
            for (int e = 0; e < 4; ++e) s += (float)xv[4 + e] * w1[e];
        }
        sitlds[i * 128 + j] = s;
    }
    __syncthreads();

    if (w < 2) {
        int i = w;
        float v0 = sitlds[i * 128 + lane];
        float v1 = sitlds[i * 128 + 64 + lane];
        float sum = v0 + v1, sq = v0 * v0 + v1 * v1;
#pragma unroll
        for (int off = 32; off >= 1; off >>= 1) {
            sum += __shfl_xor(sum, off, 64);
            sq += __shfl_xor(sq, off, 64);
        }
        float mean = sum * (1.f / 128.f);
        float rs = rsqrtf(sq * (1.f / 128.f) - mean * mean + 1e-5f);
        int b = b0 + i;
        __builtin_nontemporal_store((v0 - mean) * rs * p.olng[lane] + p.olnb[lane],
                                    &p.out[b * 128 + lane]);
        __builtin_nontemporal_store((v1 - mean) * rs * p.olng[64 + lane] + p.olnb[64 + lane],
                                    &p.out[b * 128 + 64 + lane]);
    }

    // situation_sequence: x rows 1..24 -> fp32
    for (int pp = tid; pp < G * 384; pp += 256) {
        int i = pp / 384;
        int q = pp - i * 384;
        int s = q >> 4, dp = (q & 15) * 4;
        int b = b0 + i;
        f16x4 xv = *(const f16x4*)&xlds[sw64(i * S + 1 + s, dp)];
        floatx4 o = {(float)xv[0], (float)xv[1], (float)xv[2], (float)xv[3]};
        __builtin_nontemporal_store(o, (floatx4*)&p.out[SEQOFF + b * 1536 + s * 64 + dp]);
    }
    // new_memory rows 0..8: passthrough of memory_context rows 1..9
    for (int pp = tid; pp < G * 144; pp += 256) {
        int i = pp / 144;
        int q = pp - i * 144;
        int mr = q >> 4, dp = (q & 15) * 4;
        int b = b0 + i;
        floatx4 v = *(const floatx4*)&p.mem[b * 640 + (1 + mr) * 64 + dp];
        __builtin_nontemporal_store(v, (floatx4*)&p.out[MEMOFF + b * 640 + mr * 64 + dp]);
    }
    // new_memory row 9: mean of x rows 1..24
    if (tid < G * 64) {
        int i = tid >> 6, d = tid & 63;
        float s = 0.f;
#pragma unroll
        for (int sr = 0; sr < 24; ++sr) s += (float)xlds[sw64(i * S + 1 + sr, d)];
        __builtin_nontemporal_store(s * (1.f / 24.f), &p.out[MEMOFF + (b0 + i) * 640 + 576 + d]);
    }
}

extern "C" void kernel_launch(void* const* d_in, const int* in_sizes, int n_in,
                              void* d_out, int out_size, void* d_ws, size_t ws_size,
                              hipStream_t stream) {
    (void)in_sizes; (void)n_in; (void)out_size; (void)ws_size;

    f16* ws = (f16*)d_ws;
    hipLaunchKernelGGL(cvt_all, dim3(241), dim3(256), 0, stream,
                       (const float*)d_in[11], (const float*)d_in[13],
                       (const float*)d_in[17], (const float*)d_in[19],
                       (const int*)d_in[0], (const float*)d_in[4],
                       (const float*)d_in[5], (const float*)d_in[7],
                       (const float*)d_in[9], ws);

    Params p;
    p.tok = (const int*)d_in[0];
    p.traits = (const float*)d_in[1];
    p.relg = (const float*)d_in[2];
    p.mem = (const float*)d_in[3];
    p.temb = (const float*)d_in[4];
    p.demb = (const float*)d_in[5];
    p.traitW = (const float*)d_in[6];
    p.traitb = (const float*)d_in[7];
    p.intentW = (const float*)d_in[8];
    p.intentb = (const float*)d_in[9];
    p.cls = (const float*)d_in[10];
    p.bqkv = (const float*)d_in[12];
    p.bo = (const float*)d_in[14];
    p.ln1g = (const float*)d_in[15];
    p.ln1b = (const float*)d_in[16];
    p.b1 = (const float*)d_in[18];
    p.b2 = (const float*)d_in[20];
    p.ln2g = (const float*)d_in[21];
    p.ln2b = (const float*)d_in[22];
    p.outW = (const float*)d_in[23];
    p.outb = (const float*)d_in[24];
    p.olng = (const float*)d_in[25];
    p.olnb = (const float*)d_in[26];
    p.Wqkv = ws;                 // 36864
    p.Wo = ws + 36864;           // 12288
    p.W1 = ws + 49152;           // 98304
    p.W2 = ws + 147456;          // 98304
    p.tokpos = (const float*)(ws + TOKPOS_OFF);
    p.out = (float*)d_out;

    hipLaunchKernelGGL(fused_tfm_kernel, dim3(4096 / G), dim3(256), 0, stream, p);
}